// Round 12
// baseline (1168.605 us; speedup 1.0000x reference)
//
#include <hip/hip_runtime.h>

typedef unsigned short ushort_t;
typedef unsigned int uint_t;
typedef __attribute__((ext_vector_type(8))) short v8s;   // 8 bf16 MFMA A/B frag
typedef __attribute__((ext_vector_type(4))) float v4f;   // MFMA C/D frag

#define HD 128
#define LSTR 136   // LDS weight row stride in shorts (affine offsets; 4-way read
                   // conflict accepted — cheaper than XOR swizzle, see R11)
#define MFMA16(a, b, c) __builtin_amdgcn_mfma_f32_16x16x32_bf16((a), (b), (c), 0, 0, 0)

__device__ __forceinline__ float b2f(ushort_t u) {
    union { uint_t i; float f; } v; v.i = ((uint_t)u) << 16; return v.f;
}
__device__ __forceinline__ ushort_t f2b(float f) {
    union { float f; uint_t i; } v; v.f = f;
    uint_t u = v.i;
    return (ushort_t)((u + 0x7FFFu + ((u >> 16) & 1u)) >> 16);
}

// ================= CSR build =================

__global__ __launch_bounds__(256) void k_hist(const int* __restrict__ ids,
        int* __restrict__ deg, int M, int stride) {
    int i = blockIdx.x * blockDim.x + threadIdx.x;
    if (i >= M) return;
    int id = ids[(size_t)i * stride];
    if (id >= 0) atomicAdd(&deg[id], 1);
}

__device__ __forceinline__ void scan_map(int b, int T0, int TN, int& a, int& t) {
    if (b < T0) { a = 0; t = b; }
    else { int r = b - T0; a = 1 + r / TN; t = r % TN; }
}

__global__ __launch_bounds__(1024) void k_scan_up(
        const int* d0, const int* d1, const int* d2, const int* d3,
        int* s0, int* s1, int* s2, int* s3,
        int* __restrict__ tsum, int T0, int TN, int nSK, int nN) {
    int a, t;
    scan_map(blockIdx.x, T0, TN, a, t);
    const int* d = (a == 0) ? d0 : (a == 1) ? d1 : (a == 2) ? d2 : d3;
    int* s = (a == 0) ? s0 : (a == 1) ? s1 : (a == 2) ? s2 : s3;
    int n = (a == 0) ? nSK : nN;
    __shared__ int wsum[16];
    int tdx = threadIdx.x, lane = tdx & 63, wv = tdx >> 6;
    int i = t * 1024 + tdx;
    int v = (i < n) ? d[i] : 0;
    int x = v;
    #pragma unroll
    for (int off = 1; off < 64; off <<= 1) {
        int y = __shfl_up(x, off);
        if (lane >= off) x += y;
    }
    if (lane == 63) wsum[wv] = x;
    __syncthreads();
    int wo = 0, tot = 0;
    #pragma unroll
    for (int ww = 0; ww < 16; ++ww) {
        int sv = wsum[ww];
        if (ww < wv) wo += sv;
        tot += sv;
    }
    if (i < n) s[i] = wo + (x - v);
    if (tdx == 0) tsum[a * 128 + t] = tot;
}

__global__ __launch_bounds__(256) void k_scan_mid(
        const int* __restrict__ tsum, int* __restrict__ toff,
        int* s0, int* s1, int* s2, int* s3, int T0, int TN, int nSK, int nN) {
    int a = threadIdx.x >> 6, lane = threadIdx.x & 63;
    int T = (a == 0) ? T0 : TN;
    const int* ts = tsum + a * 128;
    int* to = toff + a * 128;
    int carry = 0;
    for (int base = 0; base < T; base += 64) {
        int idx = base + lane;
        int v = (idx < T) ? ts[idx] : 0;
        int x = v;
        #pragma unroll
        for (int off = 1; off < 64; off <<= 1) {
            int y = __shfl_up(x, off);
            if (lane >= off) x += y;
        }
        if (idx < T) to[idx] = carry + (x - v);
        carry += __shfl(x, 63);
    }
    if (lane == 0) {
        int* s = (a == 0) ? s0 : (a == 1) ? s1 : (a == 2) ? s2 : s3;
        s[(a == 0) ? nSK : nN] = carry;
    }
}

__global__ __launch_bounds__(1024) void k_scan_down(
        int* s0, int* s1, int* s2, int* s3,
        const int* __restrict__ toff, int T0, int TN, int nSK, int nN) {
    int a, t;
    scan_map(blockIdx.x, T0, TN, a, t);
    int* s = (a == 0) ? s0 : (a == 1) ? s1 : (a == 2) ? s2 : s3;
    int n = (a == 0) ? nSK : nN;
    int i = t * 1024 + threadIdx.x;
    if (i < n) s[i] += toff[a * 128 + t];
}

__global__ __launch_bounds__(256) void k_fill(const int* __restrict__ ids,
        const int* __restrict__ start, int* __restrict__ cursor,
        int* __restrict__ slots, int M, int stride) {
    int i = blockIdx.x * blockDim.x + threadIdx.x;
    if (i >= M) return;
    int id = ids[(size_t)i * stride];
    if (id < 0) return;
    int pos = start[id] + atomicAdd(&cursor[id], 1);
    slots[pos] = i * stride;
}

// edge CSR fill: slots[pos] = src | (bid << 20)
__global__ __launch_bounds__(256) void k_fill_edges(const int* __restrict__ dst,
        const int* __restrict__ src, const int* __restrict__ bids,
        const int* __restrict__ start, int* __restrict__ cursor,
        int* __restrict__ slots, int E) {
    int e = blockIdx.x * blockDim.x + threadIdx.x;
    if (e >= E) return;
    int d = dst[e];
    if (d < 0) return;
    int pos = start[d] + atomicAdd(&cursor[d], 1);
    slots[pos] = src[e] | (bids[e] << 20);
}

// batch is sorted: gs[g] = first node of group g; gs[G] = N
__global__ __launch_bounds__(256) void k_gstart(const int* __restrict__ batch,
        int* __restrict__ gs, int N, int G) {
    int n = blockIdx.x * blockDim.x + threadIdx.x;
    if (n > N) return;
    int bn = (n < N) ? batch[n] : G;
    int bp = (n == 0) ? -1 : batch[n - 1];
    for (int g = bp + 1; g <= bn; ++g)
        if (g <= G) gs[g] = n;
}

// ================= weight/bias prep =================

__global__ __launch_bounds__(256) void k_convert_w(
        const float* lW1, const float* lW2, const float* gW1, const float* gW2,
        const float* skipW, const float* vvW, const float* kkW,
        const float* lbn_g, const float* gbn_g,
        ushort_t* __restrict__ wbuf, int L) {
    int idx = blockIdx.x * blockDim.x + threadIdx.x;
    int total = 7 * L * 16384;
    if (idx >= total) return;
    int fam = idx / (L * 16384);
    int r = idx % (L * 16384);
    int l = r / 16384, e = r % 16384, n = e / 128;
    const float* src;
    float sc = 1.0f;
    switch (fam) {
        case 0: src = lW1; break;
        case 1: src = lW2; sc = lbn_g[l * 128 + n]; break;
        case 2: src = gW1; break;
        case 3: src = gW2; sc = gbn_g[l * 128 + n]; break;
        case 4: src = skipW; break;
        case 5: src = vvW; break;
        default: src = kkW; break;
    }
    wbuf[idx] = f2b(src[(size_t)l * 16384 + e] * sc);
}

__global__ __launch_bounds__(256) void k_bias(
        const float* lb2, const float* lbn_g, const float* lbn_b,
        const float* skipb, const float* vvb, const float* kkb,
        const float* gb2, const float* gbn_g, const float* gbn_b,
        float* __restrict__ cb, float* __restrict__ b2g, int total) {
    int i = blockIdx.x * blockDim.x + threadIdx.x;
    if (i >= total) return;
    cb[i] = lb2[i] * lbn_g[i] + lbn_b[i] + skipb[i] + vvb[i] + kkb[i];
    b2g[i] = gb2[i] * gbn_g[i] + gbn_b[i];
}

// ================= elementwise =================

__global__ __launch_bounds__(256) void k_vf(const int* __restrict__ node_ids,
        float* __restrict__ vf, int SK) {
    int i = blockIdx.x * blockDim.x + threadIdx.x;
    if (i < SK) vf[i] = (node_ids[i] >= 0) ? 1.0f : 0.0f;
}

__global__ __launch_bounds__(256) void k_init_h(const float* __restrict__ at,
        const float* __restrict__ rt, const int* __restrict__ atom_ids,
        const float* __restrict__ vf, ushort_t* __restrict__ h, int SK) {
    int t = blockIdx.x * blockDim.x + threadIdx.x;
    int i = t >> 6, lane = t & 63;
    if (i >= SK) return;
    float2 a = ((const float2*)(at + (size_t)atom_ids[i] * HD))[lane];
    int role = ((i & 15) == 0) ? 1 : 0;
    float2 r = ((const float2*)(rt + (size_t)role * HD))[lane];
    float m = vf[i];
    uint_t o = (uint_t)f2b((a.x + r.x) * m) | ((uint_t)f2b((a.y + r.y) * m) << 16);
    *(uint_t*)(h + (size_t)i * HD + lane * 2) = o;
}

// ---- half-wave row helpers (32 lanes x 8B per row, bond table via global/L1) ----

__device__ __forceinline__ void gine_row(const ushort_t* __restrict__ X,
        const float* __restrict__ btab, const int* __restrict__ slots,
        int s0, int s1, int w, ushort_t* __restrict__ outz, int half, int hl) {
    float f0 = 0.f, f1 = 0.f, f2 = 0.f, f3 = 0.f;
    int p = s0 + half;
    for (; p + 6 < s1; p += 8) {
        uint_t e0 = slots[p], e1 = slots[p + 2], e2 = slots[p + 4], e3 = slots[p + 6];
        uint2 u0 = *(const uint2*)(X + (size_t)(e0 & 0xFFFFF) * HD + hl * 4);
        uint2 u1 = *(const uint2*)(X + (size_t)(e1 & 0xFFFFF) * HD + hl * 4);
        uint2 u2 = *(const uint2*)(X + (size_t)(e2 & 0xFFFFF) * HD + hl * 4);
        uint2 u3 = *(const uint2*)(X + (size_t)(e3 & 0xFFFFF) * HD + hl * 4);
        float4 q0 = *(const float4*)(btab + (size_t)(e0 >> 20) * HD + hl * 4);
        float4 q1 = *(const float4*)(btab + (size_t)(e1 >> 20) * HD + hl * 4);
        float4 q2 = *(const float4*)(btab + (size_t)(e2 >> 20) * HD + hl * 4);
        float4 q3 = *(const float4*)(btab + (size_t)(e3 >> 20) * HD + hl * 4);
        f0 += fmaxf(b2f((ushort_t)(u0.x & 0xFFFF)) + q0.x, 0.f)
            + fmaxf(b2f((ushort_t)(u1.x & 0xFFFF)) + q1.x, 0.f)
            + fmaxf(b2f((ushort_t)(u2.x & 0xFFFF)) + q2.x, 0.f)
            + fmaxf(b2f((ushort_t)(u3.x & 0xFFFF)) + q3.x, 0.f);
        f1 += fmaxf(b2f((ushort_t)(u0.x >> 16)) + q0.y, 0.f)
            + fmaxf(b2f((ushort_t)(u1.x >> 16)) + q1.y, 0.f)
            + fmaxf(b2f((ushort_t)(u2.x >> 16)) + q2.y, 0.f)
            + fmaxf(b2f((ushort_t)(u3.x >> 16)) + q3.y, 0.f);
        f2 += fmaxf(b2f((ushort_t)(u0.y & 0xFFFF)) + q0.z, 0.f)
            + fmaxf(b2f((ushort_t)(u1.y & 0xFFFF)) + q1.z, 0.f)
            + fmaxf(b2f((ushort_t)(u2.y & 0xFFFF)) + q2.z, 0.f)
            + fmaxf(b2f((ushort_t)(u3.y & 0xFFFF)) + q3.z, 0.f);
        f3 += fmaxf(b2f((ushort_t)(u0.y >> 16)) + q0.w, 0.f)
            + fmaxf(b2f((ushort_t)(u1.y >> 16)) + q1.w, 0.f)
            + fmaxf(b2f((ushort_t)(u2.y >> 16)) + q2.w, 0.f)
            + fmaxf(b2f((ushort_t)(u3.y >> 16)) + q3.w, 0.f);
    }
    for (; p < s1; p += 2) {
        uint_t e = slots[p];
        uint2 u = *(const uint2*)(X + (size_t)(e & 0xFFFFF) * HD + hl * 4);
        float4 q = *(const float4*)(btab + (size_t)(e >> 20) * HD + hl * 4);
        f0 += fmaxf(b2f((ushort_t)(u.x & 0xFFFF)) + q.x, 0.f);
        f1 += fmaxf(b2f((ushort_t)(u.x >> 16)) + q.y, 0.f);
        f2 += fmaxf(b2f((ushort_t)(u.y & 0xFFFF)) + q.z, 0.f);
        f3 += fmaxf(b2f((ushort_t)(u.y >> 16)) + q.w, 0.f);
    }
    f0 += __shfl(f0, hl + 32);
    f1 += __shfl(f1, hl + 32);
    f2 += __shfl(f2, hl + 32);
    f3 += __shfl(f3, hl + 32);
    if (half == 0) {
        uint2 xu = *(const uint2*)(X + (size_t)w * HD + hl * 4);
        f0 += b2f((ushort_t)(xu.x & 0xFFFF));
        f1 += b2f((ushort_t)(xu.x >> 16));
        f2 += b2f((ushort_t)(xu.y & 0xFFFF));
        f3 += b2f((ushort_t)(xu.y >> 16));
        uint2 o;
        o.x = (uint_t)f2b(f0) | ((uint_t)f2b(f1) << 16);
        o.y = (uint_t)f2b(f2) | ((uint_t)f2b(f3) << 16);
        *(uint2*)(outz + (size_t)w * HD + hl * 4) = o;
    }
}

__device__ __forceinline__ void segmean_row(const ushort_t* __restrict__ X,
        const int* __restrict__ slots, int s0, int s1, int w,
        ushort_t* __restrict__ out, int half, int hl) {
    float inv = 1.0f / fmaxf((float)(s1 - s0), 1.0f);
    float f0 = 0.f, f1 = 0.f, f2 = 0.f, f3 = 0.f;
    int p = s0 + half;
    for (; p + 6 < s1; p += 8) {
        int r0 = slots[p], r1 = slots[p + 2], r2 = slots[p + 4], r3 = slots[p + 6];
        uint2 u0 = *(const uint2*)(X + (size_t)r0 * HD + hl * 4);
        uint2 u1 = *(const uint2*)(X + (size_t)r1 * HD + hl * 4);
        uint2 u2 = *(const uint2*)(X + (size_t)r2 * HD + hl * 4);
        uint2 u3 = *(const uint2*)(X + (size_t)r3 * HD + hl * 4);
        f0 += b2f((ushort_t)(u0.x & 0xFFFF)) + b2f((ushort_t)(u1.x & 0xFFFF))
            + b2f((ushort_t)(u2.x & 0xFFFF)) + b2f((ushort_t)(u3.x & 0xFFFF));
        f1 += b2f((ushort_t)(u0.x >> 16)) + b2f((ushort_t)(u1.x >> 16))
            + b2f((ushort_t)(u2.x >> 16)) + b2f((ushort_t)(u3.x >> 16));
        f2 += b2f((ushort_t)(u0.y & 0xFFFF)) + b2f((ushort_t)(u1.y & 0xFFFF))
            + b2f((ushort_t)(u2.y & 0xFFFF)) + b2f((ushort_t)(u3.y & 0xFFFF));
        f3 += b2f((ushort_t)(u0.y >> 16)) + b2f((ushort_t)(u1.y >> 16))
            + b2f((ushort_t)(u2.y >> 16)) + b2f((ushort_t)(u3.y >> 16));
    }
    for (; p < s1; p += 2) {
        uint2 u = *(const uint2*)(X + (size_t)slots[p] * HD + hl * 4);
        f0 += b2f((ushort_t)(u.x & 0xFFFF));
        f1 += b2f((ushort_t)(u.x >> 16));
        f2 += b2f((ushort_t)(u.y & 0xFFFF));
        f3 += b2f((ushort_t)(u.y >> 16));
    }
    f0 += __shfl(f0, hl + 32);
    f1 += __shfl(f1, hl + 32);
    f2 += __shfl(f2, hl + 32);
    f3 += __shfl(f3, hl + 32);
    if (half == 0) {
        uint2 o;
        o.x = (uint_t)f2b(f0 * inv) | ((uint_t)f2b(f1 * inv) << 16);
        o.y = (uint_t)f2b(f2 * inv) | ((uint_t)f2b(f3 * inv) << 16);
        *(uint2*)(out + (size_t)w * HD + hl * 4) = o;
    }
}

// combined: rows [0,SK) intra-GINE; [SK,SK+N) node segmean; [SK+N,SK+2N) root segmean
__global__ __launch_bounds__(256) void k_gather_all(const ushort_t* __restrict__ X,
        const float* __restrict__ btab,
        const int* __restrict__ startI, const int* __restrict__ slotI,
        ushort_t* __restrict__ outz, int SK,
        const int* __restrict__ startN, const int* __restrict__ slotN,
        ushort_t* __restrict__ nmean,
        const int* __restrict__ startR, const int* __restrict__ slotR,
        ushort_t* __restrict__ rootm, int N) {
    int w = (blockIdx.x * 256 + threadIdx.x) >> 6;
    int lane = threadIdx.x & 63;
    int half = lane >> 5, hl = lane & 31;
    if (w < SK) {
        gine_row(X, btab, slotI, startI[w], startI[w + 1], w, outz, half, hl);
    } else if (w < SK + N) {
        int r = w - SK;
        segmean_row(X, slotN, startN[r], startN[r + 1], r, nmean, half, hl);
    } else if (w < SK + 2 * N) {
        int r = w - SK - N;
        segmean_row(X, slotR, startR[r], startR[r + 1], r, rootm, half, hl);
    }
}

__global__ __launch_bounds__(256) void k_segmean(const ushort_t* __restrict__ X,
        const int* __restrict__ start, const int* __restrict__ slots,
        ushort_t* __restrict__ out, int Nrows) {
    int w = (blockIdx.x * 256 + threadIdx.x) >> 6;
    int lane = threadIdx.x & 63;
    if (w >= Nrows) return;
    segmean_row(X, slots, start[w], start[w + 1], w, out, lane >> 5, lane & 31);
}

// sorted-batch pool: one block per group, contiguous node range, no atomics
__global__ __launch_bounds__(256) void k_pool2(const ushort_t* __restrict__ xsum,
        const int* __restrict__ gs, float* __restrict__ out) {
    int g = blockIdx.x;
    int t = threadIdx.x, wv = t >> 6, lane = t & 63;
    int n0 = gs[g], n1 = gs[g + 1];
    float a0 = 0.f, a1 = 0.f;
    for (int n = n0 + wv; n < n1; n += 4) {
        uint_t u = *(const uint_t*)(xsum + (size_t)n * HD + lane * 2);
        a0 += b2f((ushort_t)(u & 0xFFFF));
        a1 += b2f((ushort_t)(u >> 16));
    }
    __shared__ float red[4][128];
    red[wv][lane * 2] = a0;
    red[wv][lane * 2 + 1] = a1;
    __syncthreads();
    if (wv == 0) {
        float s0 = red[0][lane * 2] + red[1][lane * 2]
                 + red[2][lane * 2] + red[3][lane * 2];
        float s1 = red[0][lane * 2 + 1] + red[1][lane * 2 + 1]
                 + red[2][lane * 2 + 1] + red[3][lane * 2 + 1];
        *(float2*)(out + (size_t)g * HD + lane * 2) = make_float2(s0, s1);
    }
}

// ---- stage 64 weight rows (out-cols) into padded LDS: 17408B -> 8 blocks/CU ----
__device__ __forceinline__ void stage_w64(ushort_t* Wl, const ushort_t* Wb, int t) {
    #pragma unroll
    for (int it = 0; it < 4; ++it) {
        int idx = it * 256 + t;
        int row = idx >> 4, ch = idx & 15;
        *(uint4*)&Wl[row * LSTR + ch * 8] =
            *(const uint4*)(Wb + (size_t)row * 128 + ch * 8);
    }
}

// ---- GEMM core for one 64-row block: acc[j] for col (j>>2)*64 + (j&3)*16 + quad*4 ----
__device__ __forceinline__ void gemm_body(ushort_t* Wl, const ushort_t* Wb,
        const v8s* bfrag, v4f* acc, int t, int m, int quad, int first) {
    for (int hh = 0; hh < 2; ++hh) {
        if (hh || !first) __syncthreads();
        stage_w64(Wl, Wb + hh * 8192, t);
        __syncthreads();
        #pragma unroll
        for (int nt = 0; nt < 4; ++nt) {
            #pragma unroll
            for (int c = 0; c < 4; ++c) {
                v8s wf = *(const v8s*)&Wl[(nt * 16 + m) * LSTR + c * 32 + quad * 8];
                acc[hh * 4 + nt] = MFMA16(wf, bfrag[c], acc[hh * 4 + nt]);
            }
        }
    }
}

// ================= GEMM: C = maybe_relu(A @ W^T + bias) =================
__global__ __launch_bounds__(256) void k_gemm1(const ushort_t* __restrict__ A,
        const ushort_t* __restrict__ Wb, const float* __restrict__ bias,
        ushort_t* __restrict__ C, int M, int relu_flag) {
    __shared__ ushort_t Wl[64 * LSTR];
    const int t = threadIdx.x;
    int lane = t & 63, wave = t >> 6;
    int m = lane & 15, quad = lane >> 4;
    int row = blockIdx.x * 64 + wave * 16 + m;
    int ar = row < M ? row : M - 1;
    const v8s* Ar = (const v8s*)(A + (size_t)ar * HD);
    v8s bfrag[4];
    #pragma unroll
    for (int c = 0; c < 4; ++c) bfrag[c] = Ar[c * 4 + quad];
    v4f acc[8];
    #pragma unroll
    for (int j = 0; j < 8; ++j) acc[j] = (v4f){0.f, 0.f, 0.f, 0.f};
    gemm_body(Wl, Wb, bfrag, acc, t, m, quad, 1);
    if (row < M) {
        ushort_t* Cr = C + (size_t)row * HD;
        #pragma unroll
        for (int j = 0; j < 8; ++j) {
            int col = (j >> 2) * 64 + (j & 3) * 16 + quad * 4;
            float4 b = *(const float4*)(bias + col);
            float v0 = acc[j][0] + b.x, v1 = acc[j][1] + b.y;
            float v2 = acc[j][2] + b.z, v3 = acc[j][3] + b.w;
            if (relu_flag) {
                v0 = fmaxf(v0, 0.f); v1 = fmaxf(v1, 0.f);
                v2 = fmaxf(v2, 0.f); v3 = fmaxf(v3, 0.f);
            }
            uint2 o;
            o.x = (uint_t)f2b(v0) | ((uint_t)f2b(v1) << 16);
            o.y = (uint_t)f2b(v2) | ((uint_t)f2b(v3) << 16);
            *(uint2*)(Cr + col) = o;
        }
    }
}

// ================= merged: GEMM-SK (every 8th block) + gine-EG =================
__global__ __launch_bounds__(256) void k_gemm_gine(
        // gemm part: hmid = relu(zb @ W^T + bias), M rows, Mg = blocks
        const ushort_t* __restrict__ zb, const ushort_t* __restrict__ Wb,
        const float* __restrict__ bias, ushort_t* __restrict__ hmid, int M, int Mg,
        // gine part: nz = nmean + EG-agg
        const ushort_t* __restrict__ nmean, const float* __restrict__ btab,
        const int* __restrict__ startG, const int* __restrict__ slotG,
        ushort_t* __restrict__ nz, int N) {
    __shared__ ushort_t Wl[64 * LSTR];
    const int t = threadIdx.x;
    int b = blockIdx.x;
    int g = b >> 3;
    if ((b & 7) == 0 && g < Mg) {
        int lane = t & 63, wave = t >> 6;
        int m = lane & 15, quad = lane >> 4;
        int row = g * 64 + wave * 16 + m;
        int ar = row < M ? row : M - 1;
        const v8s* Ar = (const v8s*)(zb + (size_t)ar * HD);
        v8s bfrag[4];
        #pragma unroll
        for (int c = 0; c < 4; ++c) bfrag[c] = Ar[c * 4 + quad];
        v4f acc[8];
        #pragma unroll
        for (int j = 0; j < 8; ++j) acc[j] = (v4f){0.f, 0.f, 0.f, 0.f};
        gemm_body(Wl, Wb, bfrag, acc, t, m, quad, 1);
        if (row < M) {
            ushort_t* Cr = hmid + (size_t)row * HD;
            #pragma unroll
            for (int j = 0; j < 8; ++j) {
                int col = (j >> 2) * 64 + (j & 3) * 16 + quad * 4;
                float4 bb = *(const float4*)(bias + col);
                float v0 = fmaxf(acc[j][0] + bb.x, 0.f);
                float v1 = fmaxf(acc[j][1] + bb.y, 0.f);
                float v2 = fmaxf(acc[j][2] + bb.z, 0.f);
                float v3 = fmaxf(acc[j][3] + bb.w, 0.f);
                uint2 o;
                o.x = (uint_t)f2b(v0) | ((uint_t)f2b(v1) << 16);
                o.y = (uint_t)f2b(v2) | ((uint_t)f2b(v3) << 16);
                *(uint2*)(Cr + col) = o;
            }
        }
    } else {
        int cnt = ((b - 1) >> 3) + 1;
        if (cnt > Mg) cnt = Mg;
        int gb = b - cnt;                       // gine block index 0..gwN-1
        int w = (gb * 256 + t) >> 6;
        int lane = t & 63;
        if (w >= N) return;
        gine_row(nmean, btab, slotG, startG[w], startG[w + 1], w, nz,
                 lane >> 5, lane & 31);
    }
}

// ================= fused 4-GEMM tail (8 half-phases) =================
__global__ __launch_bounds__(256) void k_gemm_fused(
        const ushort_t* __restrict__ hmid, const ushort_t* __restrict__ h,
        const ushort_t* __restrict__ rootm, const ushort_t* __restrict__ h2,
        const int* __restrict__ node_ids, const float* __restrict__ vf,
        const ushort_t* __restrict__ W2g, const ushort_t* __restrict__ Wsk,
        const ushort_t* __restrict__ Wvv, const ushort_t* __restrict__ Wkk,
        const float* __restrict__ cb, ushort_t* __restrict__ hout, int M) {
    __shared__ ushort_t Wl[64 * LSTR];
    const int t = threadIdx.x;
    int lane = t & 63, wave = t >> 6;
    int m = lane & 15, quad = lane >> 4;
    int row = blockIdx.x * 64 + wave * 16 + m;
    int nid = node_ids[row];
    int nc = nid > 0 ? nid : 0;
    const ushort_t* Asrc[4];
    Asrc[0] = hmid + (size_t)row * HD;
    Asrc[1] = h + (size_t)row * HD;
    Asrc[2] = rootm + (size_t)nc * HD;
    Asrc[3] = h + (size_t)(row & ~15) * HD;
    const ushort_t* Ws[4] = {W2g, Wsk, Wvv, Wkk};
    v4f acc[8];
    #pragma unroll
    for (int j = 0; j < 8; ++j) acc[j] = (v4f){0.f, 0.f, 0.f, 0.f};
    for (int ph = 0; ph < 4; ++ph) {
        const v8s* Ar = (const v8s*)Asrc[ph];
        v8s bfrag[4];
        #pragma unroll
        for (int c = 0; c < 4; ++c) bfrag[c] = Ar[c * 4 + quad];
        gemm_body(Wl, Ws[ph], bfrag, acc, t, m, quad, ph == 0);
    }
    float vfm = vf[row];
    const ushort_t* h2r = h2 + (size_t)nc * HD;
    ushort_t* Cr = hout + (size_t)row * HD;
    #pragma unroll
    for (int j = 0; j < 8; ++j) {
        int col = (j >> 2) * 64 + (j & 3) * 16 + quad * 4;
        float4 b = *(const float4*)(cb + col);
        uint2 hh = *(const uint2*)(h2r + col);
        float v0 = acc[j][0] + b.x + b2f((ushort_t)(hh.x & 0xFFFF));
        float v1 = acc[j][1] + b.y + b2f((ushort_t)(hh.x >> 16));
        float v2 = acc[j][2] + b.z + b2f((ushort_t)(hh.y & 0xFFFF));
        float v3 = acc[j][3] + b.w + b2f((ushort_t)(hh.y >> 16));
        v0 = fmaxf(v0, 0.f) * vfm; v1 = fmaxf(v1, 0.f) * vfm;
        v2 = fmaxf(v2, 0.f) * vfm; v3 = fmaxf(v3, 0.f) * vfm;
        uint2 o;
        o.x = (uint_t)f2b(v0) | ((uint_t)f2b(v1) << 16);
        o.y = (uint_t)f2b(v2) | ((uint_t)f2b(v3) << 16);
        *(uint2*)(Cr + col) = o;
    }
}

// ================= launcher =================

extern "C" void kernel_launch(void* const* d_in, const int* in_sizes, int n_in,
                              void* d_out, int out_size, void* d_ws, size_t ws_size,
                              hipStream_t stream) {
    (void)n_in; (void)ws_size;
    const float* atom_table = (const float*)d_in[0];
    const float* bond_table = (const float*)d_in[1];
    const float* role_table = (const float*)d_in[2];
    const float* lW1 = (const float*)d_in[3];
    const float* lb1 = (const float*)d_in[4];
    const float* lW2 = (const float*)d_in[5];
    const float* lb2 = (const float*)d_in[6];
    const float* gW1 = (const float*)d_in[7];
    const float* gb1 = (const float*)d_in[8];
    const float* gW2 = (const float*)d_in[9];
    const float* gb2 = (const float*)d_in[10];
    const float* lbn_g = (const float*)d_in[11];
    const float* lbn_b = (const float*)d_in[12];
    const float* gbn_g = (const float*)d_in[13];
    const float* gbn_b = (const float*)d_in[14];
    const float* skipW = (const float*)d_in[15];
    const float* skipb = (const float*)d_in[16];
    const float* vvW = (const float*)d_in[17];
    const float* vvb = (const float*)d_in[18];
    const float* kkW = (const float*)d_in[19];
    const float* kkb = (const float*)d_in[20];
    const int* atom_ids = (const int*)d_in[21];
    const int* bond_ids_intra = (const int*)d_in[22];
    const int* bond_ids_global = (const int*)d_in[23];
    const int* intra_ei = (const int*)d_in[24];
    const int* node_ids = (const int*)d_in[25];
    const int* edge_index = (const int*)d_in[26];
    const int* batch = (const int*)d_in[28];

    const int SK = in_sizes[21];
    const int EI = in_sizes[22];
    const int EG = in_sizes[23];
    const int N  = in_sizes[28];
    const int L  = in_sizes[4] / HD;
    const int S  = SK / 16;
    const int G  = out_size / HD;

    // ---- workspace layout ----
    ushort_t* us = (ushort_t*)d_ws;
    ushort_t* hA    = us;
    ushort_t* hB    = hA + (size_t)SK * HD;
    ushort_t* hmid  = hB + (size_t)SK * HD;
    ushort_t* nmean = hmid + (size_t)SK * HD;
    ushort_t* nz    = nmean + (size_t)N * HD;
    ushort_t* nmid  = nz + (size_t)N * HD;
    ushort_t* h2    = nmid + (size_t)N * HD;
    ushort_t* rootm = h2 + (size_t)N * HD;
    ushort_t* wbuf  = rootm + (size_t)N * HD;
    float* fp = (float*)(wbuf + (size_t)7 * L * 16384);
    float* vf  = fp;
    float* cb  = vf + SK;
    float* b2g = cb + (size_t)L * 128;
    int* ip = (int*)(b2g + (size_t)L * 128);
    int* degI   = ip;
    int* degG   = degI + SK;
    int* degN   = degG + N;
    int* degR   = degN + N;
    int* startI = degR + N;
    int* startG = startI + SK + 1;
    int* startN = startG + N + 1;
    int* startR = startN + N + 1;
    int* slotI  = startR + N + 1;
    int* slotG  = slotI + EI;
    int* slotN  = slotG + EG;
    int* slotR  = slotN + SK;
    int* tsum   = slotR + S;        // 4*128
    int* toff   = tsum + 512;       // 4*128
    int* gs     = toff + 512;       // G+1

    const int B = 256;
    const int gwSK  = (SK * 64 + B - 1) / B;
    const int gwN   = (N * 64 + B - 1) / B;
    const int gwAll = ((SK + 2 * N) * 64 + B - 1) / B;
    const int ggSK  = (SK + 63) / 64;
    const int ggN   = (N + 63) / 64;
    const int* intra_src = intra_ei;
    const int* intra_dst = intra_ei + EI;
    const int* glob_src  = edge_index;
    const int* glob_dst  = edge_index + EG;

    // ---- weight/bias prep ----
    int wtot = 7 * L * 16384;
    k_convert_w<<<(wtot + B - 1) / B, B, 0, stream>>>(lW1, lW2, gW1, gW2, skipW,
            vvW, kkW, lbn_g, gbn_g, wbuf, L);
    k_bias<<<(L * 128 + B - 1) / B, B, 0, stream>>>(lb2, lbn_g, lbn_b, skipb, vvb,
            kkb, gb2, gbn_g, gbn_b, cb, b2g, L * 128);

    // ---- CSR build ----
    hipMemsetAsync(degI, 0, (size_t)(SK + 3 * N) * sizeof(int), stream);
    k_hist<<<(EI + B - 1) / B, B, 0, stream>>>(intra_dst, degI, EI, 1);
    k_hist<<<(EG + B - 1) / B, B, 0, stream>>>(glob_dst, degG, EG, 1);
    k_hist<<<(SK + B - 1) / B, B, 0, stream>>>(node_ids, degN, SK, 1);
    k_hist<<<(S + B - 1) / B, B, 0, stream>>>(node_ids, degR, S, 16);
    const int T0 = (SK + 1023) / 1024, TN = (N + 1023) / 1024;
    const int nsb = T0 + 3 * TN;
    k_scan_up<<<nsb, 1024, 0, stream>>>(degI, degG, degN, degR,
            startI, startG, startN, startR, tsum, T0, TN, SK, N);
    k_scan_mid<<<1, 256, 0, stream>>>(tsum, toff, startI, startG, startN, startR,
            T0, TN, SK, N);
    k_scan_down<<<nsb, 1024, 0, stream>>>(startI, startG, startN, startR,
            toff, T0, TN, SK, N);
    hipMemsetAsync(degI, 0, (size_t)(SK + 3 * N) * sizeof(int), stream);
    k_fill_edges<<<(EI + B - 1) / B, B, 0, stream>>>(intra_dst, intra_src,
            bond_ids_intra, startI, degI, slotI, EI);
    k_fill_edges<<<(EG + B - 1) / B, B, 0, stream>>>(glob_dst, glob_src,
            bond_ids_global, startG, degG, slotG, EG);
    k_fill<<<(SK + B - 1) / B, B, 0, stream>>>(node_ids, startN, degN, slotN, SK, 1);
    k_fill<<<(S + B - 1) / B, B, 0, stream>>>(node_ids, startR, degR, slotR, S, 16);
    k_gstart<<<(N + 1 + B - 1) / B, B, 0, stream>>>(batch, gs, N, G);

    // ---- init ----
    k_vf<<<(SK + B - 1) / B, B, 0, stream>>>(node_ids, vf, SK);
    k_init_h<<<gwSK, B, 0, stream>>>(atom_table, role_table, atom_ids, vf, hA, SK);

    ushort_t* hcur = hA;
    ushort_t* zb   = hB;
    auto WB = [&](int fam, int l) { return wbuf + ((size_t)(fam * L + l)) * 16384; };

    for (int l = 0; l < L; ++l) {
        const size_t lb = (size_t)l * HD;
        // 1) combined: zb = hcur + intra agg; nmean = node segmean; rootm = root segmean
        k_gather_all<<<gwAll, B, 0, stream>>>(hcur, bond_table,
                startI, slotI, zb, SK, startN, slotN, nmean,
                startR, slotR, rootm, N);
        // 2+3) merged: hmid = relu(zb @ lW1^T + lb1)  ||  nz = nmean + EG agg
        k_gemm_gine<<<ggSK + gwN, B, 0, stream>>>(zb, WB(0, l), lb1 + lb, hmid,
                SK, ggSK, nmean, bond_table, startG, slotG, nz, N);
        // 4) nmid = relu(nz @ gW1^T + gb1)
        k_gemm1<<<ggN, B, 0, stream>>>(nz, WB(2, l), gb1 + lb, nmid, N, 1);
        // 5) h2 = nmid @ (gW2*gbn_g)^T + (gb2*gbn_g + gbn_b)
        k_gemm1<<<ggN, B, 0, stream>>>(nmid, WB(3, l), b2g + lb, h2, N, 0);
        // 6) fused 4-GEMM tail -> zb
        k_gemm_fused<<<ggSK, B, 0, stream>>>(hmid, hcur, rootm, h2, node_ids, vf,
                WB(1, l), WB(4, l), WB(5, l), WB(6, l), cb + lb, zb, SK);
        ushort_t* tmp = hcur; hcur = zb; zb = tmp;
    }

    // final: node_embs = seg_mean(hcur); out = sorted-group sum (no atomics)
    k_segmean<<<gwN, B, 0, stream>>>(hcur, startN, slotN, nmean, N);
    k_pool2<<<G, B, 0, stream>>>(nmean, gs, (float*)d_out);
}

// Round 13
// 974.463 us; speedup vs baseline: 1.1992x; 1.1992x over previous
//
#include <hip/hip_runtime.h>

typedef unsigned short ushort_t;
typedef unsigned int uint_t;
typedef __attribute__((ext_vector_type(8))) short v8s;   // 8 bf16 MFMA A/B frag
typedef __attribute__((ext_vector_type(4))) float v4f;   // MFMA C/D frag
typedef __attribute__((ext_vector_type(2))) float v2f;   // packed f32 pair (v_pk_*)

#define HD 128
#define LSTR 136
#define MFMA16(a, b, c) __builtin_amdgcn_mfma_f32_16x16x32_bf16((a), (b), (c), 0, 0, 0)

__device__ __forceinline__ float b2f(ushort_t u) {
    union { uint_t i; float f; } v; v.i = ((uint_t)u) << 16; return v.f;
}
__device__ __forceinline__ ushort_t f2b(float f) {
    union { float f; uint_t i; } v; v.f = f;
    uint_t u = v.i;
    return (ushort_t)((u + 0x7FFFu + ((u >> 16) & 1u)) >> 16);
}
// two packed bf16 -> v2f {low, high}
__device__ __forceinline__ v2f b2f2(uint_t u) {
    union { uint_t i; float f; } lo, hi;
    lo.i = u << 16; hi.i = u & 0xFFFF0000u;
    v2f r; r.x = lo.f; r.y = hi.f; return r;
}

// ================= CSR build =================

__global__ __launch_bounds__(256) void k_hist(const int* __restrict__ ids,
        int* __restrict__ deg, int M, int stride) {
    int i = blockIdx.x * blockDim.x + threadIdx.x;
    if (i >= M) return;
    int id = ids[(size_t)i * stride];
    if (id >= 0) atomicAdd(&deg[id], 1);
}

__device__ __forceinline__ void scan_map(int b, int T0, int TN, int& a, int& t) {
    if (b < T0) { a = 0; t = b; }
    else { int r = b - T0; a = 1 + r / TN; t = r % TN; }
}

__global__ __launch_bounds__(1024) void k_scan_up(
        const int* d0, const int* d1, const int* d2, const int* d3,
        int* s0, int* s1, int* s2, int* s3,
        int* __restrict__ tsum, int T0, int TN, int nSK, int nN) {
    int a, t;
    scan_map(blockIdx.x, T0, TN, a, t);
    const int* d = (a == 0) ? d0 : (a == 1) ? d1 : (a == 2) ? d2 : d3;
    int* s = (a == 0) ? s0 : (a == 1) ? s1 : (a == 2) ? s2 : s3;
    int n = (a == 0) ? nSK : nN;
    __shared__ int wsum[16];
    int tdx = threadIdx.x, lane = tdx & 63, wv = tdx >> 6;
    int i = t * 1024 + tdx;
    int v = (i < n) ? d[i] : 0;
    int x = v;
    #pragma unroll
    for (int off = 1; off < 64; off <<= 1) {
        int y = __shfl_up(x, off);
        if (lane >= off) x += y;
    }
    if (lane == 63) wsum[wv] = x;
    __syncthreads();
    int wo = 0, tot = 0;
    #pragma unroll
    for (int ww = 0; ww < 16; ++ww) {
        int sv = wsum[ww];
        if (ww < wv) wo += sv;
        tot += sv;
    }
    if (i < n) s[i] = wo + (x - v);
    if (tdx == 0) tsum[a * 128 + t] = tot;
}

__global__ __launch_bounds__(256) void k_scan_mid(
        const int* __restrict__ tsum, int* __restrict__ toff,
        int* s0, int* s1, int* s2, int* s3, int T0, int TN, int nSK, int nN) {
    int a = threadIdx.x >> 6, lane = threadIdx.x & 63;
    int T = (a == 0) ? T0 : TN;
    const int* ts = tsum + a * 128;
    int* to = toff + a * 128;
    int carry = 0;
    for (int base = 0; base < T; base += 64) {
        int idx = base + lane;
        int v = (idx < T) ? ts[idx] : 0;
        int x = v;
        #pragma unroll
        for (int off = 1; off < 64; off <<= 1) {
            int y = __shfl_up(x, off);
            if (lane >= off) x += y;
        }
        if (idx < T) to[idx] = carry + (x - v);
        carry += __shfl(x, 63);
    }
    if (lane == 0) {
        int* s = (a == 0) ? s0 : (a == 1) ? s1 : (a == 2) ? s2 : s3;
        s[(a == 0) ? nSK : nN] = carry;
    }
}

__global__ __launch_bounds__(1024) void k_scan_down(
        int* s0, int* s1, int* s2, int* s3,
        const int* __restrict__ toff, int T0, int TN, int nSK, int nN) {
    int a, t;
    scan_map(blockIdx.x, T0, TN, a, t);
    int* s = (a == 0) ? s0 : (a == 1) ? s1 : (a == 2) ? s2 : s3;
    int n = (a == 0) ? nSK : nN;
    int i = t * 1024 + threadIdx.x;
    if (i < n) s[i] += toff[a * 128 + t];
}

__global__ __launch_bounds__(256) void k_fill(const int* __restrict__ ids,
        const int* __restrict__ start, int* __restrict__ cursor,
        int* __restrict__ slots, int M, int stride) {
    int i = blockIdx.x * blockDim.x + threadIdx.x;
    if (i >= M) return;
    int id = ids[(size_t)i * stride];
    if (id < 0) return;
    int pos = start[id] + atomicAdd(&cursor[id], 1);
    slots[pos] = i * stride;
}

__global__ __launch_bounds__(256) void k_fill_edges(const int* __restrict__ dst,
        const int* __restrict__ src, const int* __restrict__ bids,
        const int* __restrict__ start, int* __restrict__ cursor,
        int* __restrict__ slots, int E) {
    int e = blockIdx.x * blockDim.x + threadIdx.x;
    if (e >= E) return;
    int d = dst[e];
    if (d < 0) return;
    int pos = start[d] + atomicAdd(&cursor[d], 1);
    slots[pos] = src[e] | (bids[e] << 20);
}

__global__ __launch_bounds__(256) void k_gstart(const int* __restrict__ batch,
        int* __restrict__ gs, int N, int G) {
    int n = blockIdx.x * blockDim.x + threadIdx.x;
    if (n > N) return;
    int bn = (n < N) ? batch[n] : G;
    int bp = (n == 0) ? -1 : batch[n - 1];
    for (int g = bp + 1; g <= bn; ++g)
        if (g <= G) gs[g] = n;
}

// ================= weight/bias prep =================

__global__ __launch_bounds__(256) void k_convert_w(
        const float* lW1, const float* lW2, const float* gW1, const float* gW2,
        const float* skipW, const float* vvW, const float* kkW,
        const float* lbn_g, const float* gbn_g,
        ushort_t* __restrict__ wbuf, int L) {
    int idx = blockIdx.x * blockDim.x + threadIdx.x;
    int total = 7 * L * 16384;
    if (idx >= total) return;
    int fam = idx / (L * 16384);
    int r = idx % (L * 16384);
    int l = r / 16384, e = r % 16384, n = e / 128;
    const float* src;
    float sc = 1.0f;
    switch (fam) {
        case 0: src = lW1; break;
        case 1: src = lW2; sc = lbn_g[l * 128 + n]; break;
        case 2: src = gW1; break;
        case 3: src = gW2; sc = gbn_g[l * 128 + n]; break;
        case 4: src = skipW; break;
        case 5: src = vvW; break;
        default: src = kkW; break;
    }
    wbuf[idx] = f2b(src[(size_t)l * 16384 + e] * sc);
}

__global__ __launch_bounds__(256) void k_bias(
        const float* lb2, const float* lbn_g, const float* lbn_b,
        const float* skipb, const float* vvb, const float* kkb,
        const float* gb2, const float* gbn_g, const float* gbn_b,
        float* __restrict__ cb, float* __restrict__ b2g, int total) {
    int i = blockIdx.x * blockDim.x + threadIdx.x;
    if (i >= total) return;
    cb[i] = lb2[i] * lbn_g[i] + lbn_b[i] + skipb[i] + vvb[i] + kkb[i];
    b2g[i] = gb2[i] * gbn_g[i] + gbn_b[i];
}

// ================= elementwise =================

__global__ __launch_bounds__(256) void k_vf(const int* __restrict__ node_ids,
        float* __restrict__ vf, int SK) {
    int i = blockIdx.x * blockDim.x + threadIdx.x;
    if (i < SK) vf[i] = (node_ids[i] >= 0) ? 1.0f : 0.0f;
}

__global__ __launch_bounds__(256) void k_init_h(const float* __restrict__ at,
        const float* __restrict__ rt, const int* __restrict__ atom_ids,
        const float* __restrict__ vf, ushort_t* __restrict__ h, int SK) {
    int t = blockIdx.x * blockDim.x + threadIdx.x;
    int i = t >> 6, lane = t & 63;
    if (i >= SK) return;
    float2 a = ((const float2*)(at + (size_t)atom_ids[i] * HD))[lane];
    int role = ((i & 15) == 0) ? 1 : 0;
    float2 r = ((const float2*)(rt + (size_t)role * HD))[lane];
    float m = vf[i];
    uint_t o = (uint_t)f2b((a.x + r.x) * m) | ((uint_t)f2b((a.y + r.y) * m) << 16);
    *(uint_t*)(h + (size_t)i * HD + lane * 2) = o;
}

// ---- half-wave row helpers (32 lanes x 8B per row; packed v2f accumulation) ----

__device__ __forceinline__ void gine_row(const ushort_t* __restrict__ X,
        const float* __restrict__ btab, const int* __restrict__ slots,
        int s0, int s1, int w, ushort_t* __restrict__ outz, int half, int hl) {
    const v2f z = {0.f, 0.f};
    v2f a01 = z, a23 = z;
    int p = s0 + half;
    for (; p + 6 < s1; p += 8) {
        uint_t e0 = slots[p], e1 = slots[p + 2], e2 = slots[p + 4], e3 = slots[p + 6];
        uint2 u0 = *(const uint2*)(X + (size_t)(e0 & 0xFFFFF) * HD + hl * 4);
        uint2 u1 = *(const uint2*)(X + (size_t)(e1 & 0xFFFFF) * HD + hl * 4);
        uint2 u2 = *(const uint2*)(X + (size_t)(e2 & 0xFFFFF) * HD + hl * 4);
        uint2 u3 = *(const uint2*)(X + (size_t)(e3 & 0xFFFFF) * HD + hl * 4);
        float4 q0 = *(const float4*)(btab + (size_t)(e0 >> 20) * HD + hl * 4);
        float4 q1 = *(const float4*)(btab + (size_t)(e1 >> 20) * HD + hl * 4);
        float4 q2 = *(const float4*)(btab + (size_t)(e2 >> 20) * HD + hl * 4);
        float4 q3 = *(const float4*)(btab + (size_t)(e3 >> 20) * HD + hl * 4);
        v2f q001; q001.x = q0.x; q001.y = q0.y;
        v2f q023; q023.x = q0.z; q023.y = q0.w;
        v2f q101; q101.x = q1.x; q101.y = q1.y;
        v2f q123; q123.x = q1.z; q123.y = q1.w;
        v2f q201; q201.x = q2.x; q201.y = q2.y;
        v2f q223; q223.x = q2.z; q223.y = q2.w;
        v2f q301; q301.x = q3.x; q301.y = q3.y;
        v2f q323; q323.x = q3.z; q323.y = q3.w;
        a01 += __builtin_elementwise_max(b2f2(u0.x) + q001, z)
             + __builtin_elementwise_max(b2f2(u1.x) + q101, z)
             + __builtin_elementwise_max(b2f2(u2.x) + q201, z)
             + __builtin_elementwise_max(b2f2(u3.x) + q301, z);
        a23 += __builtin_elementwise_max(b2f2(u0.y) + q023, z)
             + __builtin_elementwise_max(b2f2(u1.y) + q123, z)
             + __builtin_elementwise_max(b2f2(u2.y) + q223, z)
             + __builtin_elementwise_max(b2f2(u3.y) + q323, z);
    }
    for (; p < s1; p += 2) {
        uint_t e = slots[p];
        uint2 u = *(const uint2*)(X + (size_t)(e & 0xFFFFF) * HD + hl * 4);
        float4 q = *(const float4*)(btab + (size_t)(e >> 20) * HD + hl * 4);
        v2f q01; q01.x = q.x; q01.y = q.y;
        v2f q23; q23.x = q.z; q23.y = q.w;
        a01 += __builtin_elementwise_max(b2f2(u.x) + q01, z);
        a23 += __builtin_elementwise_max(b2f2(u.y) + q23, z);
    }
    float f0 = a01.x, f1 = a01.y, f2 = a23.x, f3 = a23.y;
    f0 += __shfl(f0, hl + 32);
    f1 += __shfl(f1, hl + 32);
    f2 += __shfl(f2, hl + 32);
    f3 += __shfl(f3, hl + 32);
    if (half == 0) {
        uint2 xu = *(const uint2*)(X + (size_t)w * HD + hl * 4);
        f0 += b2f((ushort_t)(xu.x & 0xFFFF));
        f1 += b2f((ushort_t)(xu.x >> 16));
        f2 += b2f((ushort_t)(xu.y & 0xFFFF));
        f3 += b2f((ushort_t)(xu.y >> 16));
        uint2 o;
        o.x = (uint_t)f2b(f0) | ((uint_t)f2b(f1) << 16);
        o.y = (uint_t)f2b(f2) | ((uint_t)f2b(f3) << 16);
        *(uint2*)(outz + (size_t)w * HD + hl * 4) = o;
    }
}

__device__ __forceinline__ void segmean_row(const ushort_t* __restrict__ X,
        const int* __restrict__ slots, int s0, int s1, int w,
        ushort_t* __restrict__ out, int half, int hl) {
    float inv = 1.0f / fmaxf((float)(s1 - s0), 1.0f);
    const v2f z = {0.f, 0.f};
    v2f a01 = z, a23 = z;
    int p = s0 + half;
    for (; p + 6 < s1; p += 8) {
        int r0 = slots[p], r1 = slots[p + 2], r2 = slots[p + 4], r3 = slots[p + 6];
        uint2 u0 = *(const uint2*)(X + (size_t)r0 * HD + hl * 4);
        uint2 u1 = *(const uint2*)(X + (size_t)r1 * HD + hl * 4);
        uint2 u2 = *(const uint2*)(X + (size_t)r2 * HD + hl * 4);
        uint2 u3 = *(const uint2*)(X + (size_t)r3 * HD + hl * 4);
        a01 += b2f2(u0.x) + b2f2(u1.x) + b2f2(u2.x) + b2f2(u3.x);
        a23 += b2f2(u0.y) + b2f2(u1.y) + b2f2(u2.y) + b2f2(u3.y);
    }
    for (; p < s1; p += 2) {
        uint2 u = *(const uint2*)(X + (size_t)slots[p] * HD + hl * 4);
        a01 += b2f2(u.x);
        a23 += b2f2(u.y);
    }
    float f0 = a01.x, f1 = a01.y, f2 = a23.x, f3 = a23.y;
    f0 += __shfl(f0, hl + 32);
    f1 += __shfl(f1, hl + 32);
    f2 += __shfl(f2, hl + 32);
    f3 += __shfl(f3, hl + 32);
    if (half == 0) {
        uint2 o;
        o.x = (uint_t)f2b(f0 * inv) | ((uint_t)f2b(f1 * inv) << 16);
        o.y = (uint_t)f2b(f2 * inv) | ((uint_t)f2b(f3 * inv) << 16);
        *(uint2*)(out + (size_t)w * HD + hl * 4) = o;
    }
}

// combined: rows [0,SK) intra-GINE; [SK,SK+N) node segmean; [SK+N,SK+2N) root segmean
__global__ __launch_bounds__(256) void k_gather_all(const ushort_t* __restrict__ X,
        const float* __restrict__ btab,
        const int* __restrict__ startI, const int* __restrict__ slotI,
        ushort_t* __restrict__ outz, int SK,
        const int* __restrict__ startN, const int* __restrict__ slotN,
        ushort_t* __restrict__ nmean,
        const int* __restrict__ startR, const int* __restrict__ slotR,
        ushort_t* __restrict__ rootm, int N) {
    int w = (blockIdx.x * 256 + threadIdx.x) >> 6;
    int lane = threadIdx.x & 63;
    int half = lane >> 5, hl = lane & 31;
    if (w < SK) {
        gine_row(X, btab, slotI, startI[w], startI[w + 1], w, outz, half, hl);
    } else if (w < SK + N) {
        int r = w - SK;
        segmean_row(X, slotN, startN[r], startN[r + 1], r, nmean, half, hl);
    } else if (w < SK + 2 * N) {
        int r = w - SK - N;
        segmean_row(X, slotR, startR[r], startR[r + 1], r, rootm, half, hl);
    }
}

__global__ __launch_bounds__(256) void k_gine_z(const ushort_t* __restrict__ X,
        const float* __restrict__ btab, const int* __restrict__ start,
        const int* __restrict__ slots, ushort_t* __restrict__ outz, int Nrows) {
    int w = (blockIdx.x * 256 + threadIdx.x) >> 6;
    int lane = threadIdx.x & 63;
    if (w >= Nrows) return;
    gine_row(X, btab, slots, start[w], start[w + 1], w, outz, lane >> 5, lane & 31);
}

__global__ __launch_bounds__(256) void k_segmean(const ushort_t* __restrict__ X,
        const int* __restrict__ start, const int* __restrict__ slots,
        ushort_t* __restrict__ out, int Nrows) {
    int w = (blockIdx.x * 256 + threadIdx.x) >> 6;
    int lane = threadIdx.x & 63;
    if (w >= Nrows) return;
    segmean_row(X, slots, start[w], start[w + 1], w, out, lane >> 5, lane & 31);
}

// sorted-batch pool: one block per group, contiguous node range, no atomics
__global__ __launch_bounds__(256) void k_pool2(const ushort_t* __restrict__ xsum,
        const int* __restrict__ gs, float* __restrict__ out) {
    int g = blockIdx.x;
    int t = threadIdx.x, wv = t >> 6, lane = t & 63;
    int n0 = gs[g], n1 = gs[g + 1];
    float a0 = 0.f, a1 = 0.f;
    for (int n = n0 + wv; n < n1; n += 4) {
        uint_t u = *(const uint_t*)(xsum + (size_t)n * HD + lane * 2);
        a0 += b2f((ushort_t)(u & 0xFFFF));
        a1 += b2f((ushort_t)(u >> 16));
    }
    __shared__ float red[4][128];
    red[wv][lane * 2] = a0;
    red[wv][lane * 2 + 1] = a1;
    __syncthreads();
    if (wv == 0) {
        float s0 = red[0][lane * 2] + red[1][lane * 2]
                 + red[2][lane * 2] + red[3][lane * 2];
        float s1 = red[0][lane * 2 + 1] + red[1][lane * 2 + 1]
                 + red[2][lane * 2 + 1] + red[3][lane * 2 + 1];
        *(float2*)(out + (size_t)g * HD + lane * 2) = make_float2(s0, s1);
    }
}

// ---- stage one 128x128 bf16 weight into padded LDS (R9 champion form) ----
__device__ __forceinline__ void stage_w(ushort_t* Wl, const ushort_t* Wb, int t) {
    #pragma unroll
    for (int it = 0; it < 8; ++it) {
        int idx = it * 256 + t;
        uint4 v = *(const uint4*)(Wb + (size_t)idx * 8);
        int row = idx >> 4, col = (idx & 15) * 8;
        *(uint4*)&Wl[row * LSTR + col] = v;
    }
}

// ================= GEMM: C = maybe_relu(A @ W^T + bias) =================
__global__ __launch_bounds__(256) void k_gemm1(const ushort_t* __restrict__ A,
        const ushort_t* __restrict__ Wb, const float* __restrict__ bias,
        ushort_t* __restrict__ C, int M, int relu_flag) {
    __shared__ ushort_t Wl[128 * LSTR];
    const int t = threadIdx.x;
    stage_w(Wl, Wb, t);
    int lane = t & 63, wave = t >> 6;
    int m = lane & 15, quad = lane >> 4;
    int row = blockIdx.x * 64 + wave * 16 + m;
    int ar = row < M ? row : M - 1;
    const v8s* Ar = (const v8s*)(A + (size_t)ar * HD);
    v8s bfrag[4];
    #pragma unroll
    for (int c = 0; c < 4; ++c) bfrag[c] = Ar[c * 4 + quad];
    __syncthreads();
    v4f acc[8];
    #pragma unroll
    for (int nt = 0; nt < 8; ++nt) acc[nt] = (v4f){0.f, 0.f, 0.f, 0.f};
    #pragma unroll
    for (int nt = 0; nt < 8; ++nt) {
        #pragma unroll
        for (int c = 0; c < 4; ++c) {
            v8s wf = *(const v8s*)&Wl[(nt * 16 + m) * LSTR + c * 32 + quad * 8];
            acc[nt] = MFMA16(wf, bfrag[c], acc[nt]);
        }
    }
    if (row < M) {
        ushort_t* Cr = C + (size_t)row * HD;
        #pragma unroll
        for (int nt = 0; nt < 8; ++nt) {
            int col = nt * 16 + quad * 4;
            float4 b = *(const float4*)(bias + col);
            float v0 = acc[nt][0] + b.x, v1 = acc[nt][1] + b.y;
            float v2 = acc[nt][2] + b.z, v3 = acc[nt][3] + b.w;
            if (relu_flag) {
                v0 = fmaxf(v0, 0.f); v1 = fmaxf(v1, 0.f);
                v2 = fmaxf(v2, 0.f); v3 = fmaxf(v3, 0.f);
            }
            uint2 o;
            o.x = (uint_t)f2b(v0) | ((uint_t)f2b(v1) << 16);
            o.y = (uint_t)f2b(v2) | ((uint_t)f2b(v3) << 16);
            *(uint2*)(Cr + col) = o;
        }
    }
}

// ================= fused 4-GEMM tail =================
__global__ __launch_bounds__(256) void k_gemm_fused(
        const ushort_t* __restrict__ hmid, const ushort_t* __restrict__ h,
        const ushort_t* __restrict__ rootm, const ushort_t* __restrict__ h2,
        const int* __restrict__ node_ids, const float* __restrict__ vf,
        const ushort_t* __restrict__ W2g, const ushort_t* __restrict__ Wsk,
        const ushort_t* __restrict__ Wvv, const ushort_t* __restrict__ Wkk,
        const float* __restrict__ cb, ushort_t* __restrict__ hout, int M) {
    __shared__ ushort_t Wl[128 * LSTR];
    const int t = threadIdx.x;
    int lane = t & 63, wave = t >> 6;
    int m = lane & 15, quad = lane >> 4;
    int row = blockIdx.x * 64 + wave * 16 + m;
    int nid = node_ids[row];
    int nc = nid > 0 ? nid : 0;
    const ushort_t* Asrc[4];
    Asrc[0] = hmid + (size_t)row * HD;
    Asrc[1] = h + (size_t)row * HD;
    Asrc[2] = rootm + (size_t)nc * HD;
    Asrc[3] = h + (size_t)(row & ~15) * HD;
    const ushort_t* Ws[4] = {W2g, Wsk, Wvv, Wkk};
    v4f acc[8];
    #pragma unroll
    for (int nt = 0; nt < 8; ++nt) acc[nt] = (v4f){0.f, 0.f, 0.f, 0.f};
    for (int ph = 0; ph < 4; ++ph) {
        if (ph) __syncthreads();
        stage_w(Wl, Ws[ph], t);
        const v8s* Ar = (const v8s*)Asrc[ph];
        v8s bfrag[4];
        #pragma unroll
        for (int c = 0; c < 4; ++c) bfrag[c] = Ar[c * 4 + quad];
        __syncthreads();
        #pragma unroll
        for (int nt = 0; nt < 8; ++nt) {
            #pragma unroll
            for (int c = 0; c < 4; ++c) {
                v8s wf = *(const v8s*)&Wl[(nt * 16 + m) * LSTR + c * 32 + quad * 8];
                acc[nt] = MFMA16(wf, bfrag[c], acc[nt]);
            }
        }
    }
    float vfm = vf[row];
    const ushort_t* h2r = h2 + (size_t)nc * HD;
    ushort_t* Cr = hout + (size_t)row * HD;
    #pragma unroll
    for (int nt = 0; nt < 8; ++nt) {
        int col = nt * 16 + quad * 4;
        float4 b = *(const float4*)(cb + col);
        uint2 hh = *(const uint2*)(h2r + col);
        float v0 = acc[nt][0] + b.x + b2f((ushort_t)(hh.x & 0xFFFF));
        float v1 = acc[nt][1] + b.y + b2f((ushort_t)(hh.x >> 16));
        float v2 = acc[nt][2] + b.z + b2f((ushort_t)(hh.y & 0xFFFF));
        float v3 = acc[nt][3] + b.w + b2f((ushort_t)(hh.y >> 16));
        v0 = fmaxf(v0, 0.f) * vfm; v1 = fmaxf(v1, 0.f) * vfm;
        v2 = fmaxf(v2, 0.f) * vfm; v3 = fmaxf(v3, 0.f) * vfm;
        uint2 o;
        o.x = (uint_t)f2b(v0) | ((uint_t)f2b(v1) << 16);
        o.y = (uint_t)f2b(v2) | ((uint_t)f2b(v3) << 16);
        *(uint2*)(Cr + col) = o;
    }
}

// ================= launcher =================

extern "C" void kernel_launch(void* const* d_in, const int* in_sizes, int n_in,
                              void* d_out, int out_size, void* d_ws, size_t ws_size,
                              hipStream_t stream) {
    (void)n_in; (void)ws_size;
    const float* atom_table = (const float*)d_in[0];
    const float* bond_table = (const float*)d_in[1];
    const float* role_table = (const float*)d_in[2];
    const float* lW1 = (const float*)d_in[3];
    const float* lb1 = (const float*)d_in[4];
    const float* lW2 = (const float*)d_in[5];
    const float* lb2 = (const float*)d_in[6];
    const float* gW1 = (const float*)d_in[7];
    const float* gb1 = (const float*)d_in[8];
    const float* gW2 = (const float*)d_in[9];
    const float* gb2 = (const float*)d_in[10];
    const float* lbn_g = (const float*)d_in[11];
    const float* lbn_b = (const float*)d_in[12];
    const float* gbn_g = (const float*)d_in[13];
    const float* gbn_b = (const float*)d_in[14];
    const float* skipW = (const float*)d_in[15];
    const float* skipb = (const float*)d_in[16];
    const float* vvW = (const float*)d_in[17];
    const float* vvb = (const float*)d_in[18];
    const float* kkW = (const float*)d_in[19];
    const float* kkb = (const float*)d_in[20];
    const int* atom_ids = (const int*)d_in[21];
    const int* bond_ids_intra = (const int*)d_in[22];
    const int* bond_ids_global = (const int*)d_in[23];
    const int* intra_ei = (const int*)d_in[24];
    const int* node_ids = (const int*)d_in[25];
    const int* edge_index = (const int*)d_in[26];
    const int* batch = (const int*)d_in[28];

    const int SK = in_sizes[21];
    const int EI = in_sizes[22];
    const int EG = in_sizes[23];
    const int N  = in_sizes[28];
    const int L  = in_sizes[4] / HD;
    const int S  = SK / 16;
    const int G  = out_size / HD;

    // ---- workspace layout ----
    ushort_t* us = (ushort_t*)d_ws;
    ushort_t* hA    = us;
    ushort_t* hB    = hA + (size_t)SK * HD;
    ushort_t* hmid  = hB + (size_t)SK * HD;
    ushort_t* nmean = hmid + (size_t)SK * HD;
    ushort_t* nz    = nmean + (size_t)N * HD;
    ushort_t* nmid  = nz + (size_t)N * HD;
    ushort_t* h2    = nmid + (size_t)N * HD;
    ushort_t* rootm = h2 + (size_t)N * HD;
    ushort_t* wbuf  = rootm + (size_t)N * HD;
    float* fp = (float*)(wbuf + (size_t)7 * L * 16384);
    float* vf  = fp;
    float* cb  = vf + SK;
    float* b2g = cb + (size_t)L * 128;
    int* ip = (int*)(b2g + (size_t)L * 128);
    int* degI   = ip;
    int* degG   = degI + SK;
    int* degN   = degG + N;
    int* degR   = degN + N;
    int* startI = degR + N;
    int* startG = startI + SK + 1;
    int* startN = startG + N + 1;
    int* startR = startN + N + 1;
    int* slotI  = startR + N + 1;
    int* slotG  = slotI + EI;
    int* slotN  = slotG + EG;
    int* slotR  = slotN + SK;
    int* tsum   = slotR + S;        // 4*128
    int* toff   = tsum + 512;       // 4*128
    int* gs     = toff + 512;       // G+1

    const int B = 256;
    const int gwSK  = (SK * 64 + B - 1) / B;
    const int gwN   = (N * 64 + B - 1) / B;
    const int gwAll = ((SK + 2 * N) * 64 + B - 1) / B;
    const int ggSK  = (SK + 63) / 64;
    const int ggN   = (N + 63) / 64;
    const int* intra_src = intra_ei;
    const int* intra_dst = intra_ei + EI;
    const int* glob_src  = edge_index;
    const int* glob_dst  = edge_index + EG;

    // ---- weight/bias prep ----
    int wtot = 7 * L * 16384;
    k_convert_w<<<(wtot + B - 1) / B, B, 0, stream>>>(lW1, lW2, gW1, gW2, skipW,
            vvW, kkW, lbn_g, gbn_g, wbuf, L);
    k_bias<<<(L * 128 + B - 1) / B, B, 0, stream>>>(lb2, lbn_g, lbn_b, skipb, vvb,
            kkb, gb2, gbn_g, gbn_b, cb, b2g, L * 128);

    // ---- CSR build ----
    hipMemsetAsync(degI, 0, (size_t)(SK + 3 * N) * sizeof(int), stream);
    k_hist<<<(EI + B - 1) / B, B, 0, stream>>>(intra_dst, degI, EI, 1);
    k_hist<<<(EG + B - 1) / B, B, 0, stream>>>(glob_dst, degG, EG, 1);
    k_hist<<<(SK + B - 1) / B, B, 0, stream>>>(node_ids, degN, SK, 1);
    k_hist<<<(S + B - 1) / B, B, 0, stream>>>(node_ids, degR, S, 16);
    const int T0 = (SK + 1023) / 1024, TN = (N + 1023) / 1024;
    const int nsb = T0 + 3 * TN;
    k_scan_up<<<nsb, 1024, 0, stream>>>(degI, degG, degN, degR,
            startI, startG, startN, startR, tsum, T0, TN, SK, N);
    k_scan_mid<<<1, 256, 0, stream>>>(tsum, toff, startI, startG, startN, startR,
            T0, TN, SK, N);
    k_scan_down<<<nsb, 1024, 0, stream>>>(startI, startG, startN, startR,
            toff, T0, TN, SK, N);
    hipMemsetAsync(degI, 0, (size_t)(SK + 3 * N) * sizeof(int), stream);
    k_fill_edges<<<(EI + B - 1) / B, B, 0, stream>>>(intra_dst, intra_src,
            bond_ids_intra, startI, degI, slotI, EI);
    k_fill_edges<<<(EG + B - 1) / B, B, 0, stream>>>(glob_dst, glob_src,
            bond_ids_global, startG, degG, slotG, EG);
    k_fill<<<(SK + B - 1) / B, B, 0, stream>>>(node_ids, startN, degN, slotN, SK, 1);
    k_fill<<<(S + B - 1) / B, B, 0, stream>>>(node_ids, startR, degR, slotR, S, 16);
    k_gstart<<<(N + 1 + B - 1) / B, B, 0, stream>>>(batch, gs, N, G);

    // ---- init ----
    k_vf<<<(SK + B - 1) / B, B, 0, stream>>>(node_ids, vf, SK);
    k_init_h<<<gwSK, B, 0, stream>>>(atom_table, role_table, atom_ids, vf, hA, SK);

    ushort_t* hcur = hA;
    ushort_t* zb   = hB;
    auto WB = [&](int fam, int l) { return wbuf + ((size_t)(fam * L + l)) * 16384; };

    for (int l = 0; l < L; ++l) {
        const size_t lb = (size_t)l * HD;
        // 1) combined: zb = hcur + intra agg; nmean = node segmean; rootm = root segmean
        k_gather_all<<<gwAll, B, 0, stream>>>(hcur, bond_table,
                startI, slotI, zb, SK, startN, slotN, nmean,
                startR, slotR, rootm, N);
        // 2) hmid = relu(zb @ lW1^T + lb1)
        k_gemm1<<<ggSK, B, 0, stream>>>(zb, WB(0, l), lb1 + lb, hmid, SK, 1);
        // 3) nz = nmean + global-GINE agg
        k_gine_z<<<gwN, B, 0, stream>>>(nmean, bond_table, startG, slotG, nz, N);
        // 4) nmid = relu(nz @ gW1^T + gb1)
        k_gemm1<<<ggN, B, 0, stream>>>(nz, WB(2, l), gb1 + lb, nmid, N, 1);
        // 5) h2 = nmid @ (gW2*gbn_g)^T + (gb2*gbn_g + gbn_b)
        k_gemm1<<<ggN, B, 0, stream>>>(nmid, WB(3, l), b2g + lb, h2, N, 0);
        // 6) fused 4-GEMM tail -> zb
        k_gemm_fused<<<ggSK, B, 0, stream>>>(hmid, hcur, rootm, h2, node_ids, vf,
                WB(1, l), WB(4, l), WB(5, l), WB(6, l), cb + lb, zb, SK);
        ushort_t* tmp = hcur; hcur = zb; zb = tmp;
    }

    // final: node_embs = seg_mean(hcur); out = sorted-group sum (no atomics)
    k_segmean<<<gwN, B, 0, stream>>>(hcur, startN, slotN, nmean, N);
    k_pool2<<<G, B, 0, stream>>>(nmean, gs, (float*)d_out);
}

// Round 14
// 962.647 us; speedup vs baseline: 1.2139x; 1.0123x over previous
//
#include <hip/hip_runtime.h>

typedef unsigned short ushort_t;
typedef unsigned int uint_t;
typedef __attribute__((ext_vector_type(8))) short v8s;   // 8 bf16 MFMA A/B frag
typedef __attribute__((ext_vector_type(4))) float v4f;   // MFMA C/D frag
typedef __attribute__((ext_vector_type(2))) float v2f;   // packed f32 pair

#define HD 128
#define LSTR 136
#define MFMA16(a, b, c) __builtin_amdgcn_mfma_f32_16x16x32_bf16((a), (b), (c), 0, 0, 0)

__device__ __forceinline__ float b2f(ushort_t u) {
    union { uint_t i; float f; } v; v.i = ((uint_t)u) << 16; return v.f;
}
__device__ __forceinline__ ushort_t f2b(float f) {
    union { float f; uint_t i; } v; v.f = f;
    uint_t u = v.i;
    return (ushort_t)((u + 0x7FFFu + ((u >> 16) & 1u)) >> 16);
}
__device__ __forceinline__ v2f b2f2(uint_t u) {
    union { uint_t i; float f; } lo, hi;
    lo.i = u << 16; hi.i = u & 0xFFFF0000u;
    v2f r; r.x = lo.f; r.y = hi.f; return r;
}

// ================= CSR build =================

__global__ __launch_bounds__(256) void k_hist(const int* __restrict__ ids,
        int* __restrict__ deg, int M, int stride) {
    int i = blockIdx.x * blockDim.x + threadIdx.x;
    if (i >= M) return;
    int id = ids[(size_t)i * stride];
    if (id >= 0) atomicAdd(&deg[id], 1);
}

__device__ __forceinline__ void scan_map(int b, int T0, int TN, int& a, int& t) {
    if (b < T0) { a = 0; t = b; }
    else { int r = b - T0; a = 1 + r / TN; t = r % TN; }
}

__global__ __launch_bounds__(1024) void k_scan_up(
        const int* d0, const int* d1, const int* d2, const int* d3,
        int* s0, int* s1, int* s2, int* s3,
        int* __restrict__ tsum, int T0, int TN, int nSK, int nN) {
    int a, t;
    scan_map(blockIdx.x, T0, TN, a, t);
    const int* d = (a == 0) ? d0 : (a == 1) ? d1 : (a == 2) ? d2 : d3;
    int* s = (a == 0) ? s0 : (a == 1) ? s1 : (a == 2) ? s2 : s3;
    int n = (a == 0) ? nSK : nN;
    __shared__ int wsum[16];
    int tdx = threadIdx.x, lane = tdx & 63, wv = tdx >> 6;
    int i = t * 1024 + tdx;
    int v = (i < n) ? d[i] : 0;
    int x = v;
    #pragma unroll
    for (int off = 1; off < 64; off <<= 1) {
        int y = __shfl_up(x, off);
        if (lane >= off) x += y;
    }
    if (lane == 63) wsum[wv] = x;
    __syncthreads();
    int wo = 0, tot = 0;
    #pragma unroll
    for (int ww = 0; ww < 16; ++ww) {
        int sv = wsum[ww];
        if (ww < wv) wo += sv;
        tot += sv;
    }
    if (i < n) s[i] = wo + (x - v);
    if (tdx == 0) tsum[a * 128 + t] = tot;
}

__global__ __launch_bounds__(256) void k_scan_mid(
        const int* __restrict__ tsum, int* __restrict__ toff,
        int* s0, int* s1, int* s2, int* s3, int T0, int TN, int nSK, int nN) {
    int a = threadIdx.x >> 6, lane = threadIdx.x & 63;
    int T = (a == 0) ? T0 : TN;
    const int* ts = tsum + a * 128;
    int* to = toff + a * 128;
    int carry = 0;
    for (int base = 0; base < T; base += 64) {
        int idx = base + lane;
        int v = (idx < T) ? ts[idx] : 0;
        int x = v;
        #pragma unroll
        for (int off = 1; off < 64; off <<= 1) {
            int y = __shfl_up(x, off);
            if (lane >= off) x += y;
        }
        if (idx < T) to[idx] = carry + (x - v);
        carry += __shfl(x, 63);
    }
    if (lane == 0) {
        int* s = (a == 0) ? s0 : (a == 1) ? s1 : (a == 2) ? s2 : s3;
        s[(a == 0) ? nSK : nN] = carry;
    }
}

__global__ __launch_bounds__(1024) void k_scan_down(
        int* s0, int* s1, int* s2, int* s3,
        const int* __restrict__ toff, int T0, int TN, int nSK, int nN) {
    int a, t;
    scan_map(blockIdx.x, T0, TN, a, t);
    int* s = (a == 0) ? s0 : (a == 1) ? s1 : (a == 2) ? s2 : s3;
    int n = (a == 0) ? nSK : nN;
    int i = t * 1024 + threadIdx.x;
    if (i < n) s[i] += toff[a * 128 + t];
}

__global__ __launch_bounds__(256) void k_fill(const int* __restrict__ ids,
        const int* __restrict__ start, int* __restrict__ cursor,
        int* __restrict__ slots, int M, int stride) {
    int i = blockIdx.x * blockDim.x + threadIdx.x;
    if (i >= M) return;
    int id = ids[(size_t)i * stride];
    if (id < 0) return;
    int pos = start[id] + atomicAdd(&cursor[id], 1);
    slots[pos] = i * stride;
}

__global__ __launch_bounds__(256) void k_fill_edges(const int* __restrict__ dst,
        const int* __restrict__ src, const int* __restrict__ bids,
        const int* __restrict__ start, int* __restrict__ cursor,
        int* __restrict__ slots, int E) {
    int e = blockIdx.x * blockDim.x + threadIdx.x;
    if (e >= E) return;
    int d = dst[e];
    if (d < 0) return;
    int pos = start[d] + atomicAdd(&cursor[d], 1);
    slots[pos] = src[e] | (bids[e] << 20);
}

__global__ __launch_bounds__(256) void k_gstart(const int* __restrict__ batch,
        int* __restrict__ gs, int N, int G) {
    int n = blockIdx.x * blockDim.x + threadIdx.x;
    if (n > N) return;
    int bn = (n < N) ? batch[n] : G;
    int bp = (n == 0) ? -1 : batch[n - 1];
    for (int g = bp + 1; g <= bn; ++g)
        if (g <= G) gs[g] = n;
}

// ================= weight/bias prep =================

__global__ __launch_bounds__(256) void k_convert_w(
        const float* lW1, const float* lW2, const float* gW1, const float* gW2,
        const float* skipW, const float* vvW, const float* kkW,
        const float* lbn_g, const float* gbn_g,
        ushort_t* __restrict__ wbuf, int L) {
    int idx = blockIdx.x * blockDim.x + threadIdx.x;
    int total = 7 * L * 16384;
    if (idx >= total) return;
    int fam = idx / (L * 16384);
    int r = idx % (L * 16384);
    int l = r / 16384, e = r % 16384, n = e / 128;
    const float* src;
    float sc = 1.0f;
    switch (fam) {
        case 0: src = lW1; break;
        case 1: src = lW2; sc = lbn_g[l * 128 + n]; break;
        case 2: src = gW1; break;
        case 3: src = gW2; sc = gbn_g[l * 128 + n]; break;
        case 4: src = skipW; break;
        case 5: src = vvW; break;
        default: src = kkW; break;
    }
    wbuf[idx] = f2b(src[(size_t)l * 16384 + e] * sc);
}

__global__ __launch_bounds__(256) void k_bias(
        const float* lb2, const float* lbn_g, const float* lbn_b,
        const float* skipb, const float* vvb, const float* kkb,
        const float* gb2, const float* gbn_g, const float* gbn_b,
        float* __restrict__ cb, float* __restrict__ b2g, int total) {
    int i = blockIdx.x * blockDim.x + threadIdx.x;
    if (i >= total) return;
    cb[i] = lb2[i] * lbn_g[i] + lbn_b[i] + skipb[i] + vvb[i] + kkb[i];
    b2g[i] = gb2[i] * gbn_g[i] + gbn_b[i];
}

// ================= elementwise =================

__global__ __launch_bounds__(256) void k_vf(const int* __restrict__ node_ids,
        float* __restrict__ vf, int SK) {
    int i = blockIdx.x * blockDim.x + threadIdx.x;
    if (i < SK) vf[i] = (node_ids[i] >= 0) ? 1.0f : 0.0f;
}

__global__ __launch_bounds__(256) void k_init_h(const float* __restrict__ at,
        const float* __restrict__ rt, const int* __restrict__ atom_ids,
        const float* __restrict__ vf, ushort_t* __restrict__ h, int SK) {
    int t = blockIdx.x * blockDim.x + threadIdx.x;
    int i = t >> 6, lane = t & 63;
    if (i >= SK) return;
    float2 a = ((const float2*)(at + (size_t)atom_ids[i] * HD))[lane];
    int role = ((i & 15) == 0) ? 1 : 0;
    float2 r = ((const float2*)(rt + (size_t)role * HD))[lane];
    float m = vf[i];
    uint_t o = (uint_t)f2b((a.x + r.x) * m) | ((uint_t)f2b((a.y + r.y) * m) << 16);
    *(uint_t*)(h + (size_t)i * HD + lane * 2) = o;
}

// ---- half-wave row helpers; 8-edge main loop + 4-edge middle + 2-edge tail.
//      Middle loop matters: avg intra degree = 4, which never enters the main
//      loop — without it, deg-4 rows pay 2 serialized slot->X chains (R13). ----

__device__ __forceinline__ void gine_row(const ushort_t* __restrict__ X,
        const float* __restrict__ btab, const int* __restrict__ slots,
        int s0, int s1, int w, ushort_t* __restrict__ outz, int half, int hl) {
    const v2f z = {0.f, 0.f};
    v2f a01 = z, a23 = z;
    int p = s0 + half;
    for (; p + 6 < s1; p += 8) {
        uint_t e0 = slots[p], e1 = slots[p + 2], e2 = slots[p + 4], e3 = slots[p + 6];
        uint2 u0 = *(const uint2*)(X + (size_t)(e0 & 0xFFFFF) * HD + hl * 4);
        uint2 u1 = *(const uint2*)(X + (size_t)(e1 & 0xFFFFF) * HD + hl * 4);
        uint2 u2 = *(const uint2*)(X + (size_t)(e2 & 0xFFFFF) * HD + hl * 4);
        uint2 u3 = *(const uint2*)(X + (size_t)(e3 & 0xFFFFF) * HD + hl * 4);
        float4 q0 = *(const float4*)(btab + (size_t)(e0 >> 20) * HD + hl * 4);
        float4 q1 = *(const float4*)(btab + (size_t)(e1 >> 20) * HD + hl * 4);
        float4 q2 = *(const float4*)(btab + (size_t)(e2 >> 20) * HD + hl * 4);
        float4 q3 = *(const float4*)(btab + (size_t)(e3 >> 20) * HD + hl * 4);
        v2f q001; q001.x = q0.x; q001.y = q0.y;
        v2f q023; q023.x = q0.z; q023.y = q0.w;
        v2f q101; q101.x = q1.x; q101.y = q1.y;
        v2f q123; q123.x = q1.z; q123.y = q1.w;
        v2f q201; q201.x = q2.x; q201.y = q2.y;
        v2f q223; q223.x = q2.z; q223.y = q2.w;
        v2f q301; q301.x = q3.x; q301.y = q3.y;
        v2f q323; q323.x = q3.z; q323.y = q3.w;
        a01 += __builtin_elementwise_max(b2f2(u0.x) + q001, z)
             + __builtin_elementwise_max(b2f2(u1.x) + q101, z)
             + __builtin_elementwise_max(b2f2(u2.x) + q201, z)
             + __builtin_elementwise_max(b2f2(u3.x) + q301, z);
        a23 += __builtin_elementwise_max(b2f2(u0.y) + q023, z)
             + __builtin_elementwise_max(b2f2(u1.y) + q123, z)
             + __builtin_elementwise_max(b2f2(u2.y) + q223, z)
             + __builtin_elementwise_max(b2f2(u3.y) + q323, z);
    }
    for (; p + 2 < s1; p += 4) {      // middle: 2 edges/half, overlapped chains
        uint_t e0 = slots[p], e1 = slots[p + 2];
        uint2 u0 = *(const uint2*)(X + (size_t)(e0 & 0xFFFFF) * HD + hl * 4);
        uint2 u1 = *(const uint2*)(X + (size_t)(e1 & 0xFFFFF) * HD + hl * 4);
        float4 q0 = *(const float4*)(btab + (size_t)(e0 >> 20) * HD + hl * 4);
        float4 q1 = *(const float4*)(btab + (size_t)(e1 >> 20) * HD + hl * 4);
        v2f q001; q001.x = q0.x; q001.y = q0.y;
        v2f q023; q023.x = q0.z; q023.y = q0.w;
        v2f q101; q101.x = q1.x; q101.y = q1.y;
        v2f q123; q123.x = q1.z; q123.y = q1.w;
        a01 += __builtin_elementwise_max(b2f2(u0.x) + q001, z)
             + __builtin_elementwise_max(b2f2(u1.x) + q101, z);
        a23 += __builtin_elementwise_max(b2f2(u0.y) + q023, z)
             + __builtin_elementwise_max(b2f2(u1.y) + q123, z);
    }
    for (; p < s1; p += 2) {
        uint_t e = slots[p];
        uint2 u = *(const uint2*)(X + (size_t)(e & 0xFFFFF) * HD + hl * 4);
        float4 q = *(const float4*)(btab + (size_t)(e >> 20) * HD + hl * 4);
        v2f q01; q01.x = q.x; q01.y = q.y;
        v2f q23; q23.x = q.z; q23.y = q.w;
        a01 += __builtin_elementwise_max(b2f2(u.x) + q01, z);
        a23 += __builtin_elementwise_max(b2f2(u.y) + q23, z);
    }
    float f0 = a01.x, f1 = a01.y, f2 = a23.x, f3 = a23.y;
    f0 += __shfl(f0, hl + 32);
    f1 += __shfl(f1, hl + 32);
    f2 += __shfl(f2, hl + 32);
    f3 += __shfl(f3, hl + 32);
    if (half == 0) {
        uint2 xu = *(const uint2*)(X + (size_t)w * HD + hl * 4);
        f0 += b2f((ushort_t)(xu.x & 0xFFFF));
        f1 += b2f((ushort_t)(xu.x >> 16));
        f2 += b2f((ushort_t)(xu.y & 0xFFFF));
        f3 += b2f((ushort_t)(xu.y >> 16));
        uint2 o;
        o.x = (uint_t)f2b(f0) | ((uint_t)f2b(f1) << 16);
        o.y = (uint_t)f2b(f2) | ((uint_t)f2b(f3) << 16);
        *(uint2*)(outz + (size_t)w * HD + hl * 4) = o;
    }
}

__device__ __forceinline__ void segmean_row(const ushort_t* __restrict__ X,
        const int* __restrict__ slots, int s0, int s1, int w,
        ushort_t* __restrict__ out, int half, int hl) {
    float inv = 1.0f / fmaxf((float)(s1 - s0), 1.0f);
    const v2f z = {0.f, 0.f};
    v2f a01 = z, a23 = z;
    int p = s0 + half;
    for (; p + 6 < s1; p += 8) {
        int r0 = slots[p], r1 = slots[p + 2], r2 = slots[p + 4], r3 = slots[p + 6];
        uint2 u0 = *(const uint2*)(X + (size_t)r0 * HD + hl * 4);
        uint2 u1 = *(const uint2*)(X + (size_t)r1 * HD + hl * 4);
        uint2 u2 = *(const uint2*)(X + (size_t)r2 * HD + hl * 4);
        uint2 u3 = *(const uint2*)(X + (size_t)r3 * HD + hl * 4);
        a01 += b2f2(u0.x) + b2f2(u1.x) + b2f2(u2.x) + b2f2(u3.x);
        a23 += b2f2(u0.y) + b2f2(u1.y) + b2f2(u2.y) + b2f2(u3.y);
    }
    for (; p + 2 < s1; p += 4) {      // middle: 2 rows/half, overlapped chains
        int r0 = slots[p], r1 = slots[p + 2];
        uint2 u0 = *(const uint2*)(X + (size_t)r0 * HD + hl * 4);
        uint2 u1 = *(const uint2*)(X + (size_t)r1 * HD + hl * 4);
        a01 += b2f2(u0.x) + b2f2(u1.x);
        a23 += b2f2(u0.y) + b2f2(u1.y);
    }
    for (; p < s1; p += 2) {
        uint2 u = *(const uint2*)(X + (size_t)slots[p] * HD + hl * 4);
        a01 += b2f2(u.x);
        a23 += b2f2(u.y);
    }
    float f0 = a01.x, f1 = a01.y, f2 = a23.x, f3 = a23.y;
    f0 += __shfl(f0, hl + 32);
    f1 += __shfl(f1, hl + 32);
    f2 += __shfl(f2, hl + 32);
    f3 += __shfl(f3, hl + 32);
    if (half == 0) {
        uint2 o;
        o.x = (uint_t)f2b(f0 * inv) | ((uint_t)f2b(f1 * inv) << 16);
        o.y = (uint_t)f2b(f2 * inv) | ((uint_t)f2b(f3 * inv) << 16);
        *(uint2*)(out + (size_t)w * HD + hl * 4) = o;
    }
}

// combined: rows [0,SK) intra-GINE; [SK,SK+N) node segmean; [SK+N,SK+2N) root segmean
__global__ __launch_bounds__(256) void k_gather_all(const ushort_t* __restrict__ X,
        const float* __restrict__ btab,
        const int* __restrict__ startI, const int* __restrict__ slotI,
        ushort_t* __restrict__ outz, int SK,
        const int* __restrict__ startN, const int* __restrict__ slotN,
        ushort_t* __restrict__ nmean,
        const int* __restrict__ startR, const int* __restrict__ slotR,
        ushort_t* __restrict__ rootm, int N) {
    int w = (blockIdx.x * 256 + threadIdx.x) >> 6;
    int lane = threadIdx.x & 63;
    int half = lane >> 5, hl = lane & 31;
    if (w < SK) {
        gine_row(X, btab, slotI, startI[w], startI[w + 1], w, outz, half, hl);
    } else if (w < SK + N) {
        int r = w - SK;
        segmean_row(X, slotN, startN[r], startN[r + 1], r, nmean, half, hl);
    } else if (w < SK + 2 * N) {
        int r = w - SK - N;
        segmean_row(X, slotR, startR[r], startR[r + 1], r, rootm, half, hl);
    }
}

__global__ __launch_bounds__(256) void k_gine_z(const ushort_t* __restrict__ X,
        const float* __restrict__ btab, const int* __restrict__ start,
        const int* __restrict__ slots, ushort_t* __restrict__ outz, int Nrows) {
    int w = (blockIdx.x * 256 + threadIdx.x) >> 6;
    int lane = threadIdx.x & 63;
    if (w >= Nrows) return;
    gine_row(X, btab, slots, start[w], start[w + 1], w, outz, lane >> 5, lane & 31);
}

__global__ __launch_bounds__(256) void k_segmean(const ushort_t* __restrict__ X,
        const int* __restrict__ start, const int* __restrict__ slots,
        ushort_t* __restrict__ out, int Nrows) {
    int w = (blockIdx.x * 256 + threadIdx.x) >> 6;
    int lane = threadIdx.x & 63;
    if (w >= Nrows) return;
    segmean_row(X, slots, start[w], start[w + 1], w, out, lane >> 5, lane & 31);
}

// sorted-batch pool: one block per group, contiguous node range, no atomics
__global__ __launch_bounds__(256) void k_pool2(const ushort_t* __restrict__ xsum,
        const int* __restrict__ gs, float* __restrict__ out) {
    int g = blockIdx.x;
    int t = threadIdx.x, wv = t >> 6, lane = t & 63;
    int n0 = gs[g], n1 = gs[g + 1];
    float a0 = 0.f, a1 = 0.f;
    for (int n = n0 + wv; n < n1; n += 4) {
        uint_t u = *(const uint_t*)(xsum + (size_t)n * HD + lane * 2);
        a0 += b2f((ushort_t)(u & 0xFFFF));
        a1 += b2f((ushort_t)(u >> 16));
    }
    __shared__ float red[4][128];
    red[wv][lane * 2] = a0;
    red[wv][lane * 2 + 1] = a1;
    __syncthreads();
    if (wv == 0) {
        float s0 = red[0][lane * 2] + red[1][lane * 2]
                 + red[2][lane * 2] + red[3][lane * 2];
        float s1 = red[0][lane * 2 + 1] + red[1][lane * 2 + 1]
                 + red[2][lane * 2 + 1] + red[3][lane * 2 + 1];
        *(float2*)(out + (size_t)g * HD + lane * 2) = make_float2(s0, s1);
    }
}

// ---- stage one 128x128 bf16 weight into padded LDS (R9 champion form) ----
__device__ __forceinline__ void stage_w(ushort_t* Wl, const ushort_t* Wb, int t) {
    #pragma unroll
    for (int it = 0; it < 8; ++it) {
        int idx = it * 256 + t;
        uint4 v = *(const uint4*)(Wb + (size_t)idx * 8);
        int row = idx >> 4, col = (idx & 15) * 8;
        *(uint4*)&Wl[row * LSTR + col] = v;
    }
}

// ================= GEMM: C = maybe_relu(A @ W^T + bias) =================
__global__ __launch_bounds__(256) void k_gemm1(const ushort_t* __restrict__ A,
        const ushort_t* __restrict__ Wb, const float* __restrict__ bias,
        ushort_t* __restrict__ C, int M, int relu_flag) {
    __shared__ ushort_t Wl[128 * LSTR];
    const int t = threadIdx.x;
    stage_w(Wl, Wb, t);
    int lane = t & 63, wave = t >> 6;
    int m = lane & 15, quad = lane >> 4;
    int row = blockIdx.x * 64 + wave * 16 + m;
    int ar = row < M ? row : M - 1;
    const v8s* Ar = (const v8s*)(A + (size_t)ar * HD);
    v8s bfrag[4];
    #pragma unroll
    for (int c = 0; c < 4; ++c) bfrag[c] = Ar[c * 4 + quad];
    __syncthreads();
    v4f acc[8];
    #pragma unroll
    for (int nt = 0; nt < 8; ++nt) acc[nt] = (v4f){0.f, 0.f, 0.f, 0.f};
    #pragma unroll
    for (int nt = 0; nt < 8; ++nt) {
        #pragma unroll
        for (int c = 0; c < 4; ++c) {
            v8s wf = *(const v8s*)&Wl[(nt * 16 + m) * LSTR + c * 32 + quad * 8];
            acc[nt] = MFMA16(wf, bfrag[c], acc[nt]);
        }
    }
    if (row < M) {
        ushort_t* Cr = C + (size_t)row * HD;
        #pragma unroll
        for (int nt = 0; nt < 8; ++nt) {
            int col = nt * 16 + quad * 4;
            float4 b = *(const float4*)(bias + col);
            float v0 = acc[nt][0] + b.x, v1 = acc[nt][1] + b.y;
            float v2 = acc[nt][2] + b.z, v3 = acc[nt][3] + b.w;
            if (relu_flag) {
                v0 = fmaxf(v0, 0.f); v1 = fmaxf(v1, 0.f);
                v2 = fmaxf(v2, 0.f); v3 = fmaxf(v3, 0.f);
            }
            uint2 o;
            o.x = (uint_t)f2b(v0) | ((uint_t)f2b(v1) << 16);
            o.y = (uint_t)f2b(v2) | ((uint_t)f2b(v3) << 16);
            *(uint2*)(Cr + col) = o;
        }
    }
}

// ================= fused 4-GEMM tail =================
__global__ __launch_bounds__(256) void k_gemm_fused(
        const ushort_t* __restrict__ hmid, const ushort_t* __restrict__ h,
        const ushort_t* __restrict__ rootm, const ushort_t* __restrict__ h2,
        const int* __restrict__ node_ids, const float* __restrict__ vf,
        const ushort_t* __restrict__ W2g, const ushort_t* __restrict__ Wsk,
        const ushort_t* __restrict__ Wvv, const ushort_t* __restrict__ Wkk,
        const float* __restrict__ cb, ushort_t* __restrict__ hout, int M) {
    __shared__ ushort_t Wl[128 * LSTR];
    const int t = threadIdx.x;
    int lane = t & 63, wave = t >> 6;
    int m = lane & 15, quad = lane >> 4;
    int row = blockIdx.x * 64 + wave * 16 + m;
    int nid = node_ids[row];
    int nc = nid > 0 ? nid : 0;
    const ushort_t* Asrc[4];
    Asrc[0] = hmid + (size_t)row * HD;
    Asrc[1] = h + (size_t)row * HD;
    Asrc[2] = rootm + (size_t)nc * HD;
    Asrc[3] = h + (size_t)(row & ~15) * HD;
    const ushort_t* Ws[4] = {W2g, Wsk, Wvv, Wkk};
    v4f acc[8];
    #pragma unroll
    for (int nt = 0; nt < 8; ++nt) acc[nt] = (v4f){0.f, 0.f, 0.f, 0.f};
    for (int ph = 0; ph < 4; ++ph) {
        if (ph) __syncthreads();
        stage_w(Wl, Ws[ph], t);
        const v8s* Ar = (const v8s*)Asrc[ph];
        v8s bfrag[4];
        #pragma unroll
        for (int c = 0; c < 4; ++c) bfrag[c] = Ar[c * 4 + quad];
        __syncthreads();
        #pragma unroll
        for (int nt = 0; nt < 8; ++nt) {
            #pragma unroll
            for (int c = 0; c < 4; ++c) {
                v8s wf = *(const v8s*)&Wl[(nt * 16 + m) * LSTR + c * 32 + quad * 8];
                acc[nt] = MFMA16(wf, bfrag[c], acc[nt]);
            }
        }
    }
    float vfm = vf[row];
    const ushort_t* h2r = h2 + (size_t)nc * HD;
    ushort_t* Cr = hout + (size_t)row * HD;
    #pragma unroll
    for (int nt = 0; nt < 8; ++nt) {
        int col = nt * 16 + quad * 4;
        float4 b = *(const float4*)(cb + col);
        uint2 hh = *(const uint2*)(h2r + col);
        float v0 = acc[nt][0] + b.x + b2f((ushort_t)(hh.x & 0xFFFF));
        float v1 = acc[nt][1] + b.y + b2f((ushort_t)(hh.x >> 16));
        float v2 = acc[nt][2] + b.z + b2f((ushort_t)(hh.y & 0xFFFF));
        float v3 = acc[nt][3] + b.w + b2f((ushort_t)(hh.y >> 16));
        v0 = fmaxf(v0, 0.f) * vfm; v1 = fmaxf(v1, 0.f) * vfm;
        v2 = fmaxf(v2, 0.f) * vfm; v3 = fmaxf(v3, 0.f) * vfm;
        uint2 o;
        o.x = (uint_t)f2b(v0) | ((uint_t)f2b(v1) << 16);
        o.y = (uint_t)f2b(v2) | ((uint_t)f2b(v3) << 16);
        *(uint2*)(Cr + col) = o;
    }
}

// ================= launcher =================

extern "C" void kernel_launch(void* const* d_in, const int* in_sizes, int n_in,
                              void* d_out, int out_size, void* d_ws, size_t ws_size,
                              hipStream_t stream) {
    (void)n_in; (void)ws_size;
    const float* atom_table = (const float*)d_in[0];
    const float* bond_table = (const float*)d_in[1];
    const float* role_table = (const float*)d_in[2];
    const float* lW1 = (const float*)d_in[3];
    const float* lb1 = (const float*)d_in[4];
    const float* lW2 = (const float*)d_in[5];
    const float* lb2 = (const float*)d_in[6];
    const float* gW1 = (const float*)d_in[7];
    const float* gb1 = (const float*)d_in[8];
    const float* gW2 = (const float*)d_in[9];
    const float* gb2 = (const float*)d_in[10];
    const float* lbn_g = (const float*)d_in[11];
    const float* lbn_b = (const float*)d_in[12];
    const float* gbn_g = (const float*)d_in[13];
    const float* gbn_b = (const float*)d_in[14];
    const float* skipW = (const float*)d_in[15];
    const float* skipb = (const float*)d_in[16];
    const float* vvW = (const float*)d_in[17];
    const float* vvb = (const float*)d_in[18];
    const float* kkW = (const float*)d_in[19];
    const float* kkb = (const float*)d_in[20];
    const int* atom_ids = (const int*)d_in[21];
    const int* bond_ids_intra = (const int*)d_in[22];
    const int* bond_ids_global = (const int*)d_in[23];
    const int* intra_ei = (const int*)d_in[24];
    const int* node_ids = (const int*)d_in[25];
    const int* edge_index = (const int*)d_in[26];
    const int* batch = (const int*)d_in[28];

    const int SK = in_sizes[21];
    const int EI = in_sizes[22];
    const int EG = in_sizes[23];
    const int N  = in_sizes[28];
    const int L  = in_sizes[4] / HD;
    const int S  = SK / 16;
    const int G  = out_size / HD;

    // ---- workspace layout ----
    ushort_t* us = (ushort_t*)d_ws;
    ushort_t* hA    = us;
    ushort_t* hB    = hA + (size_t)SK * HD;
    ushort_t* hmid  = hB + (size_t)SK * HD;
    ushort_t* nmean = hmid + (size_t)SK * HD;
    ushort_t* nz    = nmean + (size_t)N * HD;
    ushort_t* nmid  = nz + (size_t)N * HD;
    ushort_t* h2    = nmid + (size_t)N * HD;
    ushort_t* rootm = h2 + (size_t)N * HD;
    ushort_t* wbuf  = rootm + (size_t)N * HD;
    float* fp = (float*)(wbuf + (size_t)7 * L * 16384);
    float* vf  = fp;
    float* cb  = vf + SK;
    float* b2g = cb + (size_t)L * 128;
    int* ip = (int*)(b2g + (size_t)L * 128);
    int* degI   = ip;
    int* degG   = degI + SK;
    int* degN   = degG + N;
    int* degR   = degN + N;
    int* startI = degR + N;
    int* startG = startI + SK + 1;
    int* startN = startG + N + 1;
    int* startR = startN + N + 1;
    int* slotI  = startR + N + 1;
    int* slotG  = slotI + EI;
    int* slotN  = slotG + EG;
    int* slotR  = slotN + SK;
    int* tsum   = slotR + S;        // 4*128
    int* toff   = tsum + 512;       // 4*128
    int* gs     = toff + 512;       // G+1

    const int B = 256;
    const int gwSK  = (SK * 64 + B - 1) / B;
    const int gwN   = (N * 64 + B - 1) / B;
    const int gwAll = ((SK + 2 * N) * 64 + B - 1) / B;
    const int ggSK  = (SK + 63) / 64;
    const int ggN   = (N + 63) / 64;
    const int* intra_src = intra_ei;
    const int* intra_dst = intra_ei + EI;
    const int* glob_src  = edge_index;
    const int* glob_dst  = edge_index + EG;

    // ---- weight/bias prep ----
    int wtot = 7 * L * 16384;
    k_convert_w<<<(wtot + B - 1) / B, B, 0, stream>>>(lW1, lW2, gW1, gW2, skipW,
            vvW, kkW, lbn_g, gbn_g, wbuf, L);
    k_bias<<<(L * 128 + B - 1) / B, B, 0, stream>>>(lb2, lbn_g, lbn_b, skipb, vvb,
            kkb, gb2, gbn_g, gbn_b, cb, b2g, L * 128);

    // ---- CSR build ----
    hipMemsetAsync(degI, 0, (size_t)(SK + 3 * N) * sizeof(int), stream);
    k_hist<<<(EI + B - 1) / B, B, 0, stream>>>(intra_dst, degI, EI, 1);
    k_hist<<<(EG + B - 1) / B, B, 0, stream>>>(glob_dst, degG, EG, 1);
    k_hist<<<(SK + B - 1) / B, B, 0, stream>>>(node_ids, degN, SK, 1);
    k_hist<<<(S + B - 1) / B, B, 0, stream>>>(node_ids, degR, S, 16);
    const int T0 = (SK + 1023) / 1024, TN = (N + 1023) / 1024;
    const int nsb = T0 + 3 * TN;
    k_scan_up<<<nsb, 1024, 0, stream>>>(degI, degG, degN, degR,
            startI, startG, startN, startR, tsum, T0, TN, SK, N);
    k_scan_mid<<<1, 256, 0, stream>>>(tsum, toff, startI, startG, startN, startR,
            T0, TN, SK, N);
    k_scan_down<<<nsb, 1024, 0, stream>>>(startI, startG, startN, startR,
            toff, T0, TN, SK, N);
    hipMemsetAsync(degI, 0, (size_t)(SK + 3 * N) * sizeof(int), stream);
    k_fill_edges<<<(EI + B - 1) / B, B, 0, stream>>>(intra_dst, intra_src,
            bond_ids_intra, startI, degI, slotI, EI);
    k_fill_edges<<<(EG + B - 1) / B, B, 0, stream>>>(glob_dst, glob_src,
            bond_ids_global, startG, degG, slotG, EG);
    k_fill<<<(SK + B - 1) / B, B, 0, stream>>>(node_ids, startN, degN, slotN, SK, 1);
    k_fill<<<(S + B - 1) / B, B, 0, stream>>>(node_ids, startR, degR, slotR, S, 16);
    k_gstart<<<(N + 1 + B - 1) / B, B, 0, stream>>>(batch, gs, N, G);

    // ---- init ----
    k_vf<<<(SK + B - 1) / B, B, 0, stream>>>(node_ids, vf, SK);
    k_init_h<<<gwSK, B, 0, stream>>>(atom_table, role_table, atom_ids, vf, hA, SK);

    ushort_t* hcur = hA;
    ushort_t* zb   = hB;
    auto WB = [&](int fam, int l) { return wbuf + ((size_t)(fam * L + l)) * 16384; };

    for (int l = 0; l < L; ++l) {
        const size_t lb = (size_t)l * HD;
        // 1) combined: zb = hcur + intra agg; nmean = node segmean; rootm = root segmean
        k_gather_all<<<gwAll, B, 0, stream>>>(hcur, bond_table,
                startI, slotI, zb, SK, startN, slotN, nmean,
                startR, slotR, rootm, N);
        // 2) hmid = relu(zb @ lW1^T + lb1)
        k_gemm1<<<ggSK, B, 0, stream>>>(zb, WB(0, l), lb1 + lb, hmid, SK, 1);
        // 3) nz = nmean + global-GINE agg
        k_gine_z<<<gwN, B, 0, stream>>>(nmean, bond_table, startG, slotG, nz, N);
        // 4) nmid = relu(nz @ gW1^T + gb1)
        k_gemm1<<<ggN, B, 0, stream>>>(nz, WB(2, l), gb1 + lb, nmid, N, 1);
        // 5) h2 = nmid @ (gW2*gbn_g)^T + (gb2*gbn_g + gbn_b)
        k_gemm1<<<ggN, B, 0, stream>>>(nmid, WB(3, l), b2g + lb, h2, N, 0);
        // 6) fused 4-GEMM tail -> zb
        k_gemm_fused<<<ggSK, B, 0, stream>>>(hmid, hcur, rootm, h2, node_ids, vf,
                WB(1, l), WB(4, l), WB(5, l), WB(6, l), cb + lb, zb, SK);
        ushort_t* tmp = hcur; hcur = zb; zb = tmp;
    }

    // final: node_embs = seg_mean(hcur); out = sorted-group sum (no atomics)
    k_segmean<<<gwN, B, 0, stream>>>(hcur, startN, slotN, nmean, N);
    k_pool2<<<G, B, 0, stream>>>(nmean, gs, (float*)d_out);
}